// Round 12
// baseline (1650.681 us; speedup 1.0000x reference)
//
#include <hip/hip_runtime.h>
#include <hip/hip_bf16.h>
#include <stdint.h>

#define D_MODEL 256
#define N_TOK   21760
#define BATCH   2
#define M_TOT   (BATCH*N_TOK)   // 43520 = 170*256
#define NLAY    6

typedef __hip_bfloat16 bf16;
typedef short bf16x8 __attribute__((ext_vector_type(8)));
typedef float f32x4  __attribute__((ext_vector_type(4)));

// packed per-layer weight block (bf16, transposed to [N][K])
#define WVSA_SZ (640*256)
#define WO_SZ   (256*256)
#define W1_SZ   (1024*256)
#define W2_SZ   (256*1024)
#define PER_L   (WVSA_SZ+WO_SZ+W1_SZ+W2_SZ)  // 753664

// ---- workspace layout (aliased by lifetime), total ~165.4 MB ----
#define SZ_QF   ((size_t)M_TOT*256*4)
#define SZ_BF   ((size_t)M_TOT*256*2)
#define SZ_AW   ((size_t)M_TOT*128*4)
#define SZ_WP   ((size_t)PER_L*NLAY*2)
#define SZ_BP   ((size_t)NLAY*640*4)
#define OFF_QPOS  ((size_t)0)
#define OFF_QB    (OFF_QPOS + SZ_BF)
#define OFF_QPB   (OFF_QB   + SZ_BF)    // sampled | delta2
#define OFF_WP    (OFF_QPB  + SZ_BF)
#define OFF_BP    (OFF_WP   + SZ_WP)
#define OFF_R1    (OFF_BP   + SZ_BP)    // offb f32 | hidden (spans R1+VAL+AW)
#define OFF_VAL   (OFF_R1   + SZ_QF)    // value bf16 | delta1 bf16
#define OFF_AW    (OFF_VAL  + SZ_BF)
#define WS_NEED   (OFF_AW   + SZ_AW)

// ---------------------------------------------------------------- helpers
typedef const __attribute__((address_space(1))) void gvoid_t;
typedef __attribute__((address_space(3))) void lvoid_t;
__device__ __forceinline__ void gload_lds16(const void* g, void* l){
    __builtin_amdgcn_global_load_lds((gvoid_t*)g, (lvoid_t*)l, 16, 0, 0);
}
__device__ __forceinline__ float bfu(ushort u){ return __uint_as_float(((uint)u)<<16); }
__device__ __forceinline__ ushort f2b(float f){ return __bfloat16_as_ushort(__float2bfloat16(f)); }
__device__ __forceinline__ float bf16_lo(uint u){ return __uint_as_float(u << 16); }
__device__ __forceinline__ float bf16_hi(uint u){ return __uint_as_float(u & 0xffff0000u); }

// ---------------------------------------------------------------- sentinel
__global__ void sentinel_kernel(float* out) { out[0] = 1.0e6f; }

// ---------------------------------------------------------------- pack
__global__ void pack_kernel(const float* __restrict__ Wv, const float* __restrict__ Ws,
                            const float* __restrict__ Wa, const float* __restrict__ Wo,
                            const float* __restrict__ W1, const float* __restrict__ W2,
                            const float* __restrict__ bv, const float* __restrict__ bso,
                            const float* __restrict__ ba,
                            bf16* __restrict__ wp, float* __restrict__ bp)
{
    const int WTOT = PER_L * NLAY;
    for (int idx = blockIdx.x*blockDim.x + threadIdx.x; idx < WTOT + NLAY*640;
         idx += gridDim.x*blockDim.x) {
        if (idx < WTOT) {
            int l = idx / PER_L, r = idx - l*PER_L;
            float v;
            if (r < WVSA_SZ) {                       // Wvsa_t[640][256]
                int n = r >> 8, k = r & 255;
                if (n < 256)      v = Wv[((size_t)l*256+k)*256 + n];
                else if (n < 512) v = Ws[((size_t)l*256+k)*256 + (n-256)];
                else              v = Wa[((size_t)l*256+k)*128 + (n-512)];
            } else if (r < WVSA_SZ+WO_SZ) {          // Wo_t[256][256]
                int j = r - WVSA_SZ; int n = j >> 8, k = j & 255;
                v = Wo[((size_t)l*256+k)*256 + n];
            } else if (r < WVSA_SZ+WO_SZ+W1_SZ) {    // W1_t[1024][256]
                int j = r - (WVSA_SZ+WO_SZ); int n = j >> 8, k = j & 255;
                v = W1[((size_t)l*256+k)*1024 + n];
            } else {                                 // W2_t[256][1024]
                int j = r - (WVSA_SZ+WO_SZ+W1_SZ); int n = j >> 10, k = j & 1023;
                v = W2[((size_t)l*1024+k)*256 + n];
            }
            wp[idx] = __float2bfloat16(v);
        } else {
            int i = idx - WTOT; int l = i / 640, n = i - l*640;
            float v = (n < 256) ? bv[l*256+n]
                    : (n < 512) ? bso[l*256+(n-256)]
                                : ba[l*128+(n-512)];
            bp[l*640+n] = v;
        }
    }
}

// ---------------------------------------------------------------- prep (src transpose)
__device__ __forceinline__ void tile_decode(int st, int& lvl, int& s0, int& hw, int& start)
{
    if (st < 256)      { lvl=0; s0=st*64;       hw=16384; start=0; }
    else if (st < 320) { lvl=1; s0=(st-256)*64; hw=4096;  start=16384; }
    else if (st < 336) { lvl=2; s0=(st-320)*64; hw=1024;  start=20480; }
    else               { lvl=3; s0=(st-336)*64; hw=256;   start=21504; }
}

__global__ __launch_bounds__(256) void prep_pos_kernel(
    const float* __restrict__ p0, const float* __restrict__ p1,
    const float* __restrict__ p2, const float* __restrict__ p3,
    const float* __restrict__ le, bf16* __restrict__ qpos)
{
    __shared__ float tile[32][65];
    int lvl, s0, hw, start; tile_decode(blockIdx.x, lvl, s0, hw, start);
    const float* sp = lvl==0?p0 : lvl==1?p1 : lvl==2?p2 : p3;
    const int t = threadIdx.x, b = blockIdx.z, c0 = blockIdx.y*32;
#pragma unroll
    for (int j=0;j<8;++j){
        int cl = j*4 + (t>>6), sl = t&63;
        tile[cl][sl] = sp[((size_t)b*256 + c0+cl)*hw + s0 + sl];
    }
    __syncthreads();
#pragma unroll
    for (int j=0;j<8;++j){
        int sl = j*8 + (t>>5), cl = t&31;
        float v = tile[cl][sl] + le[lvl*256 + c0 + cl];
        size_t o = ((size_t)b*N_TOK + start + s0 + sl)*256 + c0 + cl;
        qpos[o] = __float2bfloat16(v);
    }
}

__global__ __launch_bounds__(256) void prep_q_kernel(
    const float* __restrict__ s0p, const float* __restrict__ s1p,
    const float* __restrict__ s2p, const float* __restrict__ s3p,
    const bf16* __restrict__ qpos,
    bf16* __restrict__ qb, bf16* __restrict__ qpb)
{
    __shared__ float tile[32][65];
    int lvl, s0, hw, start; tile_decode(blockIdx.x, lvl, s0, hw, start);
    const float* sp = lvl==0?s0p : lvl==1?s1p : lvl==2?s2p : s3p;
    const int t = threadIdx.x, b = blockIdx.z, c0 = blockIdx.y*32;
#pragma unroll
    for (int j=0;j<8;++j){
        int cl = j*4 + (t>>6), sl = t&63;
        tile[cl][sl] = sp[((size_t)b*256 + c0+cl)*hw + s0 + sl];
    }
    __syncthreads();
#pragma unroll
    for (int j=0;j<8;++j){
        int sl = j*8 + (t>>5), cl = t&31;
        float v = tile[cl][sl];
        size_t o = ((size_t)b*N_TOK + start + s0 + sl)*256 + c0 + cl;
        qb[o] = __float2bfloat16(v);
        qpb[o] = __float2bfloat16(v + __bfloat162float(qpos[o]));
    }
}

// ---------------------------------------------------------------- GEMM (bf16 MFMA)
// BM=256 x BN=128 tile, 8 waves (4 wr x 2 wc), 512 threads; each wave owns 64x64.
// Double-buffered LDS 2-phase pipeline: issue next-tile global_load_lds FIRST
// (3 instrs/thread), s_waitcnt vmcnt(3) (current tile done; next in flight across
// the RAW barrier), compute, lgkmcnt(0)+sched_barrier(0), barrier.
template<int MODE>
__global__ __launch_bounds__(512) void gemm_kernel(
    const bf16* __restrict__ A, const bf16* __restrict__ A2,
    const bf16* __restrict__ Wt, const float* __restrict__ bias,
    int K, void* __restrict__ out0, void* __restrict__ out1, void* __restrict__ out2)
{
    __shared__ __align__(1024) ushort As[2][256*32];
    __shared__ __align__(1024) ushort Bs[2][128*32];
    const int tid = threadIdx.x;
    const int lane = tid & 63, w = tid >> 6;
    const int wr = w >> 1, wc = w & 1;
    const int lr = lane & 15, lg = lane >> 4;
    const size_t m0 = (size_t)blockIdx.x * 256;
    const int n0 = blockIdx.y * 128;
    const bf16* Ause = (MODE == 0 && n0 >= 256) ? A2 : A;

    const int srow = tid >> 2;        // 0..127
    const int sphys = tid & 3;
    const int KSTEPS = K >> 5;

    auto stage = [&](int ks, int buf){
        const int k0 = ks*32;
#pragma unroll
        for (int j=0;j<2;++j){
            int row  = srow + j*128;
            int slot = sphys ^ ((row>>1)&3);
            gload_lds16(&Ause[(m0+row)*(size_t)K + k0 + slot*8], &As[buf][row*32 + sphys*8]);
        }
        {
            int row  = srow;
            int slot = sphys ^ ((row>>1)&3);
            gload_lds16(&Wt[(size_t)(n0+row)*K + k0 + slot*8],   &Bs[buf][row*32 + sphys*8]);
        }
    };

    f32x4 acc[4][4];
#pragma unroll
    for (int i=0;i<4;++i)
#pragma unroll
        for (int j=0;j<4;++j) acc[i][j] = (f32x4){0.f,0.f,0.f,0.f};

    stage(0, 0);
    for (int ks = 0; ks < KSTEPS; ++ks) {
        const int cur = ks & 1;
        if (ks + 1 < KSTEPS) {
            stage(ks + 1, cur ^ 1);
            asm volatile("s_waitcnt vmcnt(3)" ::: "memory");
        } else {
            asm volatile("s_waitcnt vmcnt(0)" ::: "memory");
        }
        __builtin_amdgcn_s_barrier();
        bf16x8 av[4], bw[4];
#pragma unroll
        for (int i=0;i<4;++i){
            int ar = wr*64 + i*16 + lr;
            int br = wc*64 + i*16 + lr;
            av[i] = *(bf16x8*)&As[cur][ar*32 + ((lg ^ ((ar>>1)&3))<<3)];
            bw[i] = *(bf16x8*)&Bs[cur][br*32 + ((lg ^ ((br>>1)&3))<<3)];
        }
#pragma unroll
        for (int mi=0;mi<4;++mi)
#pragma unroll
            for (int ni=0;ni<4;++ni)
                acc[mi][ni] = __builtin_amdgcn_mfma_f32_16x16x32_bf16(av[mi], bw[ni], acc[mi][ni], 0,0,0);
        asm volatile("s_waitcnt lgkmcnt(0)" ::: "memory");
        __builtin_amdgcn_sched_barrier(0);
        __builtin_amdgcn_s_barrier();
    }
#pragma unroll
    for (int mi=0;mi<4;++mi){
#pragma unroll
        for (int ni=0;ni<4;++ni){
            int gr0 = (int)m0 + wr*64 + mi*16 + lg*4;
            int gc  = n0 + wc*64 + ni*16 + lr;
            float bb = bias[gc];
#pragma unroll
            for (int r=0;r<4;++r){
                float y = acc[mi][ni][r] + bb;
                size_t row = (size_t)(gr0 + r);
                if (MODE == 0) {
                    if (gc < 256)      ((bf16*)out0)[row*256 + gc] = __float2bfloat16(y);
                    else if (gc < 512) ((float*)out1)[row*256 + (gc-256)] = y;
                    else               ((float*)out2)[row*128 + (gc-512)] = y;
                } else if (MODE == 1) {
                    ((bf16*)out0)[row*256 + gc] = __float2bfloat16(y);
                } else {
                    ((bf16*)out0)[row*1024 + gc] = __float2bfloat16(fmaxf(y, 0.f));
                }
            }
        }
    }
}

// ---------------------------------------------------------------- deformable sampling
__global__ __launch_bounds__(256) void sample_kernel(
    const bf16* __restrict__ value, const float* __restrict__ offb,
    const float* __restrict__ awb, bf16* __restrict__ sampled)
{
    __shared__ float tabw[4][136][4];
    __shared__ int   tabo[4][136][4];
    const int nb = gridDim.x;                 // 10880, % 8 == 0
    const int chunk = nb >> 3;
    const int bid = (blockIdx.x & 7) * chunk + (blockIdx.x >> 3);
    const int wv = threadIdx.x >> 6, lane = threadIdx.x & 63;
    const int m = bid*4 + wv;

    const int b = m / N_TOK;
    const int n = m - b*N_TOK;
    float refx, refy;
    if (n < 16384)      { int s=n;       int qy=s>>7, qx=s&127; refx=(qx+0.5f)*(1.f/128.f); refy=(qy+0.5f)*(1.f/128.f); }
    else if (n < 20480) { int s=n-16384; int qy=s>>6, qx=s&63;  refx=(qx+0.5f)*(1.f/64.f);  refy=(qy+0.5f)*(1.f/64.f); }
    else if (n < 21504) { int s=n-20480; int qy=s>>5, qx=s&31;  refx=(qx+0.5f)*(1.f/32.f);  refy=(qy+0.5f)*(1.f/32.f); }
    else                { int s=n-21504; int qy=s>>4, qx=s&15;  refx=(qx+0.5f)*(1.f/16.f);  refy=(qy+0.5f)*(1.f/16.f); }

    float2 lgt = *(const float2*)&awb[(size_t)m*128 + lane*2];
    float mx = fmaxf(lgt.x, lgt.y);
#pragma unroll
    for (int o=1;o<8;o<<=1) mx = fmaxf(mx, __shfl_xor(mx, o));
    float e0 = __expf(lgt.x - mx), e1 = __expf(lgt.y - mx);
    float sm = e0 + e1;
#pragma unroll
    for (int o=1;o<8;o<<=1) sm += __shfl_xor(sm, o);
    float rs = __frcp_rn(sm);
    float wgt0 = e0 * rs, wgt1 = e1 * rs;

    float4 o4 = *(const float4*)&offb[(size_t)m*256 + lane*4];

    const int LSTART[4] = {0, 16384, 20480, 21504};
#pragma unroll
    for (int j=0;j<2;++j){
        int pg  = lane*2 + j;
        int lvl = (pg >> 2) & 3;
        int wl  = 128 >> lvl;
        float offx = j ? o4.z : o4.x;
        float offy = j ? o4.w : o4.y;
        float wgt  = j ? wgt1 : wgt0;
        float fx = refx*(float)wl - 0.5f + offx;
        float fy = refy*(float)wl - 0.5f + offy;
        float x0f = floorf(fx), y0f = floorf(fy);
        float dx = fx - x0f, dy = fy - y0f;
        int ix = (int)x0f, iy = (int)y0f;
        int cx0 = min(max(ix,0),   wl-1), cx1 = min(max(ix+1,0), wl-1);
        int cy0 = min(max(iy,0),   wl-1), cy1 = min(max(iy+1,0), wl-1);
        bool vx0 = (unsigned)ix     < (unsigned)wl, vx1 = (unsigned)(ix+1) < (unsigned)wl;
        bool vy0 = (unsigned)iy     < (unsigned)wl, vy1 = (unsigned)(iy+1) < (unsigned)wl;
        float a = 1.f-dx, bb = 1.f-dy;
        int slot = (pg >> 4)*17 + (pg & 15);
        float4 wq;
        wq.x = (vx0&&vy0) ? a*bb*wgt : 0.f;
        wq.y = (vx1&&vy0) ? dx*bb*wgt : 0.f;
        wq.z = (vx0&&vy1) ? a*dy*wgt : 0.f;
        wq.w = (vx1&&vy1) ? dx*dy*wgt : 0.f;
        *(float4*)&tabw[wv][slot][0] = wq;
        int lb = LSTART[lvl];
        int4 oq;
        oq.x = (lb + cy0*wl + cx0) << 9;
        oq.y = (lb + cy0*wl + cx1) << 9;
        oq.z = (lb + cy1*wl + cx0) << 9;
        oq.w = (lb + cy1*wl + cx1) << 9;
        *(int4*)&tabo[wv][slot][0] = oq;
    }
    __syncthreads();

    const int h = lane >> 3, c = lane & 7;
    const int rb = __builtin_amdgcn_readfirstlane(b);
    const char* vb = (const char*)value + (size_t)rb*N_TOK*512;
    const int laneoff = (h*32 + c*4)*2;
    f32x4 acc = (f32x4){0.f,0.f,0.f,0.f};
#pragma unroll 4
    for (int k=0;k<16;++k){
        int slot = h*17 + k;
        float4 w  = *(const float4*)&tabw[wv][slot][0];
        int4   io = *(const int4*)  &tabo[wv][slot][0];
        uint2 q00 = *(const uint2*)(vb + (io.x + laneoff));
        uint2 q01 = *(const uint2*)(vb + (io.y + laneoff));
        uint2 q10 = *(const uint2*)(vb + (io.z + laneoff));
        uint2 q11 = *(const uint2*)(vb + (io.w + laneoff));
        acc[0] += w.x*bf16_lo(q00.x) + w.y*bf16_lo(q01.x) + w.z*bf16_lo(q10.x) + w.w*bf16_lo(q11.x);
        acc[1] += w.x*bf16_hi(q00.x) + w.y*bf16_hi(q01.x) + w.z*bf16_hi(q10.x) + w.w*bf16_hi(q11.x);
        acc[2] += w.x*bf16_lo(q00.y) + w.y*bf16_lo(q01.y) + w.z*bf16_lo(q10.y) + w.w*bf16_lo(q11.y);
        acc[3] += w.x*bf16_hi(q00.y) + w.y*bf16_hi(q01.y) + w.z*bf16_hi(q10.y) + w.w*bf16_hi(q11.y);
    }
    ushort4 outv;
    outv.x = f2b(acc[0]);
    outv.y = f2b(acc[1]);
    outv.z = f2b(acc[2]);
    outv.w = f2b(acc[3]);
    *(ushort4*)&sampled[(size_t)m*256 + h*32 + c*4] = outv;
}

// ---------------------------------------------------------------- residual + LN
template<bool WRITE_QPB>
__global__ __launch_bounds__(256) void ln_kernel(
    bf16* __restrict__ qb, const bf16* __restrict__ delta,
    const float* __restrict__ g, const float* __restrict__ be,
    const bf16* __restrict__ qpos, bf16* __restrict__ qpb, float* __restrict__ dout)
{
    const int wv = threadIdx.x >> 6, lane = threadIdx.x & 63;
    const size_t o = ((size_t)blockIdx.x*4 + wv)*256 + lane*4;
    ushort4 qv = *(const ushort4*)&qb[o];
    ushort4 dv = *(const ushort4*)&delta[o];
    float x0 = bfu(qv.x) + bfu(dv.x);
    float x1 = bfu(qv.y) + bfu(dv.y);
    float x2 = bfu(qv.z) + bfu(dv.z);
    float x3 = bfu(qv.w) + bfu(dv.w);
    float s1 = x0+x1+x2+x3;
    float s2 = x0*x0+x1*x1+x2*x2+x3*x3;
#pragma unroll
    for (int i=1;i<64;i<<=1){ s1 += __shfl_xor(s1,i); s2 += __shfl_xor(s2,i); }
    float mu  = s1 * (1.f/256.f);
    float var = s2 * (1.f/256.f) - mu*mu;
    float rs  = rsqrtf(var + 1e-5f);
    float4 gv = *(const float4*)&g[lane*4];
    float4 bv = *(const float4*)&be[lane*4];
    float y0 = (x0-mu)*rs*gv.x + bv.x;
    float y1 = (x1-mu)*rs*gv.y + bv.y;
    float y2 = (x2-mu)*rs*gv.z + bv.z;
    float y3 = (x3-mu)*rs*gv.w + bv.w;
    ushort4 qo; qo.x=f2b(y0); qo.y=f2b(y1); qo.z=f2b(y2); qo.w=f2b(y3);
    *(ushort4*)&qb[o] = qo;
    if constexpr (WRITE_QPB) {
        ushort4 pv = *(const ushort4*)&qpos[o];
        ushort4 po;
        po.x = f2b(y0 + bfu(pv.x));
        po.y = f2b(y1 + bfu(pv.y));
        po.z = f2b(y2 + bfu(pv.z));
        po.w = f2b(y3 + bfu(pv.w));
        *(ushort4*)&qpb[o] = po;
    }
    if (dout) { *(float4*)&dout[o] = make_float4(y0,y1,y2,y3); }
}

// ---------------------------------------------------------------- launch
extern "C" void kernel_launch(void* const* d_in, const int* in_sizes, int n_in,
                              void* d_out, int out_size, void* d_ws, size_t ws_size,
                              hipStream_t stream)
{
    // setup_inputs() dict order is INTERLEAVED: src0,pos0,src1,pos1,...
    const float* src0 = (const float*)d_in[0];
    const float* pos0 = (const float*)d_in[1];
    const float* src1 = (const float*)d_in[2];
    const float* pos1 = (const float*)d_in[3];
    const float* src2 = (const float*)d_in[4];
    const float* pos2 = (const float*)d_in[5];
    const float* src3 = (const float*)d_in[6];
    const float* pos3 = (const float*)d_in[7];
    const float* le   = (const float*)d_in[8];
    const float* Wv   = (const float*)d_in[9];
    const float* bv   = (const float*)d_in[10];
    const float* Ws   = (const float*)d_in[11];
    const float* bso  = (const float*)d_in[12];
    const float* Wa   = (const float*)d_in[13];
    const float* ba   = (const float*)d_in[14];
    const float* Wo   = (const float*)d_in[15];
    const float* bo   = (const float*)d_in[16];
    const float* g1   = (const float*)d_in[17];
    const float* be1  = (const float*)d_in[18];
    const float* W1   = (const float*)d_in[19];
    const float* b1   = (const float*)d_in[20];
    const float* W2   = (const float*)d_in[21];
    const float* b2   = (const float*)d_in[22];
    const float* g2   = (const float*)d_in[23];
    const float* be2  = (const float*)d_in[24];

    if (ws_size < WS_NEED) {   // diagnostic: absmax ~1e6 means ws too small
        sentinel_kernel<<<1, 1, 0, stream>>>((float*)d_out);
        return;
    }
    char* ws = (char*)d_ws;
    bf16*  qpos   = (bf16*) (ws + OFF_QPOS);
    bf16*  qb     = (bf16*) (ws + OFF_QB);
    bf16*  qpb    = (bf16*) (ws + OFF_QPB);
    bf16*  sampled= (bf16*) (ws + OFF_QPB);   // alias: qpb dead after gemm0
    bf16*  delta2 = (bf16*) (ws + OFF_QPB);   // FFN out; ln2 reads then writes qpb in place
    bf16*  wp     = (bf16*) (ws + OFF_WP);
    float* bp     = (float*)(ws + OFF_BP);
    float* offb   = (float*)(ws + OFF_R1);    // gemm0 -> sample
    bf16*  hidden = (bf16*) (ws + OFF_R1);    // FFN: spans R1+VAL+AW (89.13 MB, exact)
    bf16*  value  = (bf16*) (ws + OFF_VAL);   // gemm0 -> sample
    bf16*  delta1 = (bf16*) (ws + OFF_VAL);   // gemm1 -> ln1 (value dead by then)
    float* awb    = (float*)(ws + OFF_AW);

    pack_kernel<<<dim3(4096), 256, 0, stream>>>(Wv, Ws, Wa, Wo, W1, W2, bv, bso, ba, wp, bp);
    prep_pos_kernel<<<dim3(340,8,2), 256, 0, stream>>>(pos0,pos1,pos2,pos3, le, qpos);
    prep_q_kernel<<<dim3(340,8,2), 256, 0, stream>>>(src0,src1,src2,src3, qpos, qb, qpb);

    for (int l = 0; l < NLAY; ++l) {
        const bf16* wl_ = wp + (size_t)l*PER_L;
        gemm_kernel<0><<<dim3(170,5), 512, 0, stream>>>(qb, qpb, wl_, bp + l*640, 256,
                                                        value, offb, awb);
        sample_kernel<<<dim3(M_TOT/4), 256, 0, stream>>>(value, offb, awb, sampled);
        gemm_kernel<1><<<dim3(170,2), 512, 0, stream>>>(sampled, nullptr, wl_ + WVSA_SZ,
                                                        bo + l*256, 256, delta1, nullptr, nullptr);
        ln_kernel<false><<<dim3(M_TOT/4), 256, 0, stream>>>(qb, delta1, g1 + l*256, be1 + l*256,
                                                            nullptr, nullptr, nullptr);
        gemm_kernel<2><<<dim3(170,8), 512, 0, stream>>>(qb, nullptr, wl_ + WVSA_SZ + WO_SZ,
                                                        b1 + l*1024, 256, hidden, nullptr, nullptr);
        gemm_kernel<1><<<dim3(170,2), 512, 0, stream>>>(hidden, nullptr,
                                                        wl_ + WVSA_SZ + WO_SZ + W1_SZ,
                                                        b2 + l*256, 1024, delta2, nullptr, nullptr);
        ln_kernel<true><<<dim3(M_TOT/4), 256, 0, stream>>>(qb, delta2, g2 + l*256, be2 + l*256,
                                                           qpos, qpb, (l==NLAY-1) ? (float*)d_out : nullptr);
    }
}

// Round 13
// 1513.626 us; speedup vs baseline: 1.0905x; 1.0905x over previous
//
#include <hip/hip_runtime.h>
#include <hip/hip_bf16.h>
#include <stdint.h>

#define D_MODEL 256
#define N_TOK   21760
#define BATCH   2
#define M_TOT   (BATCH*N_TOK)   // 43520 = 340*128
#define NLAY    6

typedef __hip_bfloat16 bf16;
typedef short bf16x8 __attribute__((ext_vector_type(8)));
typedef float f32x4  __attribute__((ext_vector_type(4)));

// packed per-layer weight block (bf16, transposed to [N][K])
#define WVSA_SZ (640*256)
#define WO_SZ   (256*256)
#define W1_SZ   (1024*256)
#define W2_SZ   (256*1024)
#define PER_L   (WVSA_SZ+WO_SZ+W1_SZ+W2_SZ)  // 753664

// ---- workspace layout (aliased by lifetime), total ~165.4 MB ----
#define SZ_QF   ((size_t)M_TOT*256*4)
#define SZ_BF   ((size_t)M_TOT*256*2)
#define SZ_AW   ((size_t)M_TOT*128*4)
#define SZ_WP   ((size_t)PER_L*NLAY*2)
#define SZ_BP   ((size_t)NLAY*640*4)
#define OFF_QPOS  ((size_t)0)
#define OFF_QB    (OFF_QPOS + SZ_BF)
#define OFF_QPB   (OFF_QB   + SZ_BF)    // sampled | delta2
#define OFF_WP    (OFF_QPB  + SZ_BF)
#define OFF_BP    (OFF_WP   + SZ_WP)
#define OFF_R1    (OFF_BP   + SZ_BP)    // offb f32 | hidden (spans R1+VAL+AW)
#define OFF_VAL   (OFF_R1   + SZ_QF)    // value bf16 | delta1 bf16
#define OFF_AW    (OFF_VAL  + SZ_BF)
#define WS_NEED   (OFF_AW   + SZ_AW)

// ---------------------------------------------------------------- helpers
typedef const __attribute__((address_space(1))) void gvoid_t;
typedef __attribute__((address_space(3))) void lvoid_t;
__device__ __forceinline__ void gload_lds16(const void* g, void* l){
    __builtin_amdgcn_global_load_lds((gvoid_t*)g, (lvoid_t*)l, 16, 0, 0);
}
__device__ __forceinline__ float bfu(ushort u){ return __uint_as_float(((uint)u)<<16); }
__device__ __forceinline__ ushort f2b(float f){ return __bfloat16_as_ushort(__float2bfloat16(f)); }
__device__ __forceinline__ float bf16_lo(uint u){ return __uint_as_float(u << 16); }
__device__ __forceinline__ float bf16_hi(uint u){ return __uint_as_float(u & 0xffff0000u); }

// ---------------------------------------------------------------- sentinel
__global__ void sentinel_kernel(float* out) { out[0] = 1.0e6f; }

// ---------------------------------------------------------------- pack
__global__ void pack_kernel(const float* __restrict__ Wv, const float* __restrict__ Ws,
                            const float* __restrict__ Wa, const float* __restrict__ Wo,
                            const float* __restrict__ W1, const float* __restrict__ W2,
                            const float* __restrict__ bv, const float* __restrict__ bso,
                            const float* __restrict__ ba,
                            bf16* __restrict__ wp, float* __restrict__ bp)
{
    const int WTOT = PER_L * NLAY;
    for (int idx = blockIdx.x*blockDim.x + threadIdx.x; idx < WTOT + NLAY*640;
         idx += gridDim.x*blockDim.x) {
        if (idx < WTOT) {
            int l = idx / PER_L, r = idx - l*PER_L;
            float v;
            if (r < WVSA_SZ) {                       // Wvsa_t[640][256]
                int n = r >> 8, k = r & 255;
                if (n < 256)      v = Wv[((size_t)l*256+k)*256 + n];
                else if (n < 512) v = Ws[((size_t)l*256+k)*256 + (n-256)];
                else              v = Wa[((size_t)l*256+k)*128 + (n-512)];
            } else if (r < WVSA_SZ+WO_SZ) {          // Wo_t[256][256]
                int j = r - WVSA_SZ; int n = j >> 8, k = j & 255;
                v = Wo[((size_t)l*256+k)*256 + n];
            } else if (r < WVSA_SZ+WO_SZ+W1_SZ) {    // W1_t[1024][256]
                int j = r - (WVSA_SZ+WO_SZ); int n = j >> 8, k = j & 255;
                v = W1[((size_t)l*256+k)*1024 + n];
            } else {                                 // W2_t[256][1024]
                int j = r - (WVSA_SZ+WO_SZ+W1_SZ); int n = j >> 10, k = j & 1023;
                v = W2[((size_t)l*1024+k)*256 + n];
            }
            wp[idx] = __float2bfloat16(v);
        } else {
            int i = idx - WTOT; int l = i / 640, n = i - l*640;
            float v = (n < 256) ? bv[l*256+n]
                    : (n < 512) ? bso[l*256+(n-256)]
                                : ba[l*128+(n-512)];
            bp[l*640+n] = v;
        }
    }
}

// ---------------------------------------------------------------- prep (src transpose)
__device__ __forceinline__ void tile_decode(int st, int& lvl, int& s0, int& hw, int& start)
{
    if (st < 256)      { lvl=0; s0=st*64;       hw=16384; start=0; }
    else if (st < 320) { lvl=1; s0=(st-256)*64; hw=4096;  start=16384; }
    else if (st < 336) { lvl=2; s0=(st-320)*64; hw=1024;  start=20480; }
    else               { lvl=3; s0=(st-336)*64; hw=256;   start=21504; }
}

__global__ __launch_bounds__(256) void prep_pos_kernel(
    const float* __restrict__ p0, const float* __restrict__ p1,
    const float* __restrict__ p2, const float* __restrict__ p3,
    const float* __restrict__ le, bf16* __restrict__ qpos)
{
    __shared__ float tile[32][65];
    int lvl, s0, hw, start; tile_decode(blockIdx.x, lvl, s0, hw, start);
    const float* sp = lvl==0?p0 : lvl==1?p1 : lvl==2?p2 : p3;
    const int t = threadIdx.x, b = blockIdx.z, c0 = blockIdx.y*32;
#pragma unroll
    for (int j=0;j<8;++j){
        int cl = j*4 + (t>>6), sl = t&63;
        tile[cl][sl] = sp[((size_t)b*256 + c0+cl)*hw + s0 + sl];
    }
    __syncthreads();
#pragma unroll
    for (int j=0;j<8;++j){
        int sl = j*8 + (t>>5), cl = t&31;
        float v = tile[cl][sl] + le[lvl*256 + c0 + cl];
        size_t o = ((size_t)b*N_TOK + start + s0 + sl)*256 + c0 + cl;
        qpos[o] = __float2bfloat16(v);
    }
}

__global__ __launch_bounds__(256) void prep_q_kernel(
    const float* __restrict__ s0p, const float* __restrict__ s1p,
    const float* __restrict__ s2p, const float* __restrict__ s3p,
    const bf16* __restrict__ qpos,
    bf16* __restrict__ qb, bf16* __restrict__ qpb)
{
    __shared__ float tile[32][65];
    int lvl, s0, hw, start; tile_decode(blockIdx.x, lvl, s0, hw, start);
    const float* sp = lvl==0?s0p : lvl==1?s1p : lvl==2?s2p : s3p;
    const int t = threadIdx.x, b = blockIdx.z, c0 = blockIdx.y*32;
#pragma unroll
    for (int j=0;j<8;++j){
        int cl = j*4 + (t>>6), sl = t&63;
        tile[cl][sl] = sp[((size_t)b*256 + c0+cl)*hw + s0 + sl];
    }
    __syncthreads();
#pragma unroll
    for (int j=0;j<8;++j){
        int sl = j*8 + (t>>5), cl = t&31;
        float v = tile[cl][sl];
        size_t o = ((size_t)b*N_TOK + start + s0 + sl)*256 + c0 + cl;
        qb[o] = __float2bfloat16(v);
        qpb[o] = __float2bfloat16(v + __bfloat162float(qpos[o]));
    }
}

// ---------------------------------------------------------------- GEMM (bf16 MFMA)
// 128x128 tile, 4 waves 2x2 (round-11 config: best measured). Double-buffered
// 2-phase pipeline: stage next FIRST, vmcnt(4), raw barrier, compute,
// lgkmcnt(0)+sched_barrier(0), barrier.
template<int MODE>
__global__ __launch_bounds__(256) void gemm_kernel(
    const bf16* __restrict__ A, const bf16* __restrict__ A2,
    const bf16* __restrict__ Wt, const float* __restrict__ bias,
    int K, void* __restrict__ out0, void* __restrict__ out1, void* __restrict__ out2)
{
    __shared__ __align__(1024) ushort As[2][128*32];
    __shared__ __align__(1024) ushort Bs[2][128*32];
    const int tid = threadIdx.x;
    const int lane = tid & 63, w = tid >> 6;
    const int wr = w >> 1, wc = w & 1;
    const int lr = lane & 15, lg = lane >> 4;
    const size_t m0 = (size_t)blockIdx.x * 128;
    const int n0 = blockIdx.y * 128;
    const bf16* Ause = (MODE == 0 && n0 >= 256) ? A2 : A;

    const int srow0 = (w<<5) + (lane>>2);
    const int sphys = (lane&3);
    const int KSTEPS = K >> 5;

    auto stage = [&](int ks, int buf){
        const int k0 = ks*32;
#pragma unroll
        for (int j=0;j<2;++j){
            int row  = srow0 + j*16;
            int slot = sphys ^ ((row>>1)&3);  // pre-swizzled global source
            gload_lds16(&Ause[(m0+row)*(size_t)K + k0 + slot*8], &As[buf][row*32 + sphys*8]);
            gload_lds16(&Wt[(size_t)(n0+row)*K + k0 + slot*8],   &Bs[buf][row*32 + sphys*8]);
        }
    };

    f32x4 acc[4][4];
#pragma unroll
    for (int i=0;i<4;++i)
#pragma unroll
        for (int j=0;j<4;++j) acc[i][j] = (f32x4){0.f,0.f,0.f,0.f};

    stage(0, 0);
    for (int ks = 0; ks < KSTEPS; ++ks) {
        const int cur = ks & 1;
        if (ks + 1 < KSTEPS) {
            stage(ks + 1, cur ^ 1);
            asm volatile("s_waitcnt vmcnt(4)" ::: "memory");
        } else {
            asm volatile("s_waitcnt vmcnt(0)" ::: "memory");
        }
        __builtin_amdgcn_s_barrier();
        bf16x8 av[4], bw[4];
#pragma unroll
        for (int i=0;i<4;++i){
            int ar = wr*64 + i*16 + lr;
            int br = wc*64 + i*16 + lr;
            av[i] = *(bf16x8*)&As[cur][ar*32 + ((lg ^ ((ar>>1)&3))<<3)];
            bw[i] = *(bf16x8*)&Bs[cur][br*32 + ((lg ^ ((br>>1)&3))<<3)];
        }
#pragma unroll
        for (int mi=0;mi<4;++mi)
#pragma unroll
            for (int ni=0;ni<4;++ni)
                acc[mi][ni] = __builtin_amdgcn_mfma_f32_16x16x32_bf16(av[mi], bw[ni], acc[mi][ni], 0,0,0);
        asm volatile("s_waitcnt lgkmcnt(0)" ::: "memory");
        __builtin_amdgcn_sched_barrier(0);
        __builtin_amdgcn_s_barrier();
    }
#pragma unroll
    for (int mi=0;mi<4;++mi){
#pragma unroll
        for (int ni=0;ni<4;++ni){
            int gr0 = (int)m0 + wr*64 + mi*16 + lg*4;
            int gc  = n0 + wc*64 + ni*16 + lr;
            float bb = bias[gc];
#pragma unroll
            for (int r=0;r<4;++r){
                float y = acc[mi][ni][r] + bb;
                size_t row = (size_t)(gr0 + r);
                if (MODE == 0) {
                    if (gc < 256)      ((bf16*)out0)[row*256 + gc] = __float2bfloat16(y);
                    else if (gc < 512) ((float*)out1)[row*256 + (gc-256)] = y;
                    else               ((float*)out2)[row*128 + (gc-512)] = y;
                } else if (MODE == 1) {
                    ((bf16*)out0)[row*256 + gc] = __float2bfloat16(y);
                } else {
                    ((bf16*)out0)[row*1024 + gc] = __float2bfloat16(fmaxf(y, 0.f));
                }
            }
        }
    }
}

// ---------------------------------------------------------------- deformable sampling
// One wave per 2 tokens: lane = t*32 + h*4 + c; each lane gathers uint4 (16B =
// 8 channels) per tap -> gather-request count HALVED vs 8B/lane. Phase 1: each
// lane computes 4 points' weights/offsets (its own 4 softmax logits). XCD-swizzled.
__global__ __launch_bounds__(256) void sample_kernel(
    const bf16* __restrict__ value, const float* __restrict__ offb,
    const float* __restrict__ awb, bf16* __restrict__ sampled)
{
    __shared__ float tabw[8][136][4];
    __shared__ int   tabo[8][136][4];
    const int nb = gridDim.x;                 // 5440, % 8 == 0
    const int chunk = nb >> 3;
    const int bid = (blockIdx.x & 7) * chunk + (blockIdx.x >> 3);
    const int wv = threadIdx.x >> 6, lane = threadIdx.x & 63;
    const int t = lane >> 5, L = lane & 31;
    const int tt = wv*2 + t;                  // token slot in block (0..7)
    const int m = bid*8 + tt;

    const int b = m / N_TOK;                  // uniform per block (21760 % 8 == 0)
    const int n = m - b*N_TOK;
    float refx, refy;
    if (n < 16384)      { int s=n;       int qy=s>>7, qx=s&127; refx=(qx+0.5f)*(1.f/128.f); refy=(qy+0.5f)*(1.f/128.f); }
    else if (n < 20480) { int s=n-16384; int qy=s>>6, qx=s&63;  refx=(qx+0.5f)*(1.f/64.f);  refy=(qy+0.5f)*(1.f/64.f); }
    else if (n < 21504) { int s=n-20480; int qy=s>>5, qx=s&31;  refx=(qx+0.5f)*(1.f/32.f);  refy=(qy+0.5f)*(1.f/32.f); }
    else                { int s=n-21504; int qy=s>>4, qx=s&15;  refx=(qx+0.5f)*(1.f/16.f);  refy=(qy+0.5f)*(1.f/16.f); }

    // softmax: 4 logits/lane; head group = 4 lanes (xor 1,2 stays in group)
    float4 lg = *(const float4*)&awb[(size_t)m*128 + L*4];
    float mx = fmaxf(fmaxf(lg.x,lg.y), fmaxf(lg.z,lg.w));
    mx = fmaxf(mx, __shfl_xor(mx,1));
    mx = fmaxf(mx, __shfl_xor(mx,2));
    float e0=__expf(lg.x-mx), e1=__expf(lg.y-mx), e2=__expf(lg.z-mx), e3=__expf(lg.w-mx);
    float sm = e0+e1+e2+e3;
    sm += __shfl_xor(sm,1);
    sm += __shfl_xor(sm,2);
    float rs = __frcp_rn(sm);
    float wgt[4] = {e0*rs, e1*rs, e2*rs, e3*rs};

    // offsets: 8 floats/lane = points 4L..4L+3
    float4 oA = *(const float4*)&offb[(size_t)m*256 + L*8];
    float4 oB = *(const float4*)&offb[(size_t)m*256 + L*8 + 4];
    float offx[4] = {oA.x, oA.z, oB.x, oB.z};
    float offy[4] = {oA.y, oA.w, oB.y, oB.w};

    const int LSTART[4] = {0, 16384, 20480, 21504};
#pragma unroll
    for (int j=0;j<4;++j){
        int pg  = L*4 + j;
        int lvl = (pg >> 2) & 3;
        int wl  = 128 >> lvl;
        float fx = refx*(float)wl - 0.5f + offx[j];
        float fy = refy*(float)wl - 0.5f + offy[j];
        float x0f = floorf(fx), y0f = floorf(fy);
        float dx = fx - x0f, dy = fy - y0f;
        int ix = (int)x0f, iy = (int)y0f;
        int cx0 = min(max(ix,0),   wl-1), cx1 = min(max(ix+1,0), wl-1);
        int cy0 = min(max(iy,0),   wl-1), cy1 = min(max(iy+1,0), wl-1);
        bool vx0 = (unsigned)ix     < (unsigned)wl, vx1 = (unsigned)(ix+1) < (unsigned)wl;
        bool vy0 = (unsigned)iy     < (unsigned)wl, vy1 = (unsigned)(iy+1) < (unsigned)wl;
        float a = 1.f-dx, bb = 1.f-dy;
        int slot = (pg >> 4)*17 + (pg & 15);
        float4 wq;
        wq.x = (vx0&&vy0) ? a*bb*wgt[j] : 0.f;
        wq.y = (vx1&&vy0) ? dx*bb*wgt[j] : 0.f;
        wq.z = (vx0&&vy1) ? a*dy*wgt[j] : 0.f;
        wq.w = (vx1&&vy1) ? dx*dy*wgt[j] : 0.f;
        *(float4*)&tabw[tt][slot][0] = wq;
        int lb = LSTART[lvl];
        int4 oq;
        oq.x = (lb + cy0*wl + cx0) << 9;
        oq.y = (lb + cy0*wl + cx1) << 9;
        oq.z = (lb + cy1*wl + cx0) << 9;
        oq.w = (lb + cy1*wl + cx1) << 9;
        *(int4*)&tabo[tt][slot][0] = oq;
    }
    __syncthreads();

    const int h = (lane >> 2) & 7, c = lane & 3;
    const int rb = __builtin_amdgcn_readfirstlane(b);
    const char* vb = (const char*)value + (size_t)rb*N_TOK*512;
    const int laneoff = h*64 + c*16;          // byte offset of 8-channel group
    f32x4 accA = (f32x4){0.f,0.f,0.f,0.f};
    f32x4 accB = (f32x4){0.f,0.f,0.f,0.f};
#pragma unroll 4
    for (int k=0;k<16;++k){
        int slot = h*17 + k;
        float4 w  = *(const float4*)&tabw[tt][slot][0];
        int4   io = *(const int4*)  &tabo[tt][slot][0];
        uint4 q00 = *(const uint4*)(vb + (io.x + laneoff));
        uint4 q01 = *(const uint4*)(vb + (io.y + laneoff));
        uint4 q10 = *(const uint4*)(vb + (io.z + laneoff));
        uint4 q11 = *(const uint4*)(vb + (io.w + laneoff));
        accA[0] += w.x*bf16_lo(q00.x) + w.y*bf16_lo(q01.x) + w.z*bf16_lo(q10.x) + w.w*bf16_lo(q11.x);
        accA[1] += w.x*bf16_hi(q00.x) + w.y*bf16_hi(q01.x) + w.z*bf16_hi(q10.x) + w.w*bf16_hi(q11.x);
        accA[2] += w.x*bf16_lo(q00.y) + w.y*bf16_lo(q01.y) + w.z*bf16_lo(q10.y) + w.w*bf16_lo(q11.y);
        accA[3] += w.x*bf16_hi(q00.y) + w.y*bf16_hi(q01.y) + w.z*bf16_hi(q10.y) + w.w*bf16_hi(q11.y);
        accB[0] += w.x*bf16_lo(q00.z) + w.y*bf16_lo(q01.z) + w.z*bf16_lo(q10.z) + w.w*bf16_lo(q11.z);
        accB[1] += w.x*bf16_hi(q00.z) + w.y*bf16_hi(q01.z) + w.z*bf16_hi(q10.z) + w.w*bf16_hi(q11.z);
        accB[2] += w.x*bf16_lo(q00.w) + w.y*bf16_lo(q01.w) + w.z*bf16_lo(q10.w) + w.w*bf16_lo(q11.w);
        accB[3] += w.x*bf16_hi(q00.w) + w.y*bf16_hi(q01.w) + w.z*bf16_hi(q10.w) + w.w*bf16_hi(q11.w);
    }
    uint4 outv;
    outv.x = (uint)f2b(accA[0]) | ((uint)f2b(accA[1])<<16);
    outv.y = (uint)f2b(accA[2]) | ((uint)f2b(accA[3])<<16);
    outv.z = (uint)f2b(accB[0]) | ((uint)f2b(accB[1])<<16);
    outv.w = (uint)f2b(accB[2]) | ((uint)f2b(accB[3])<<16);
    *(uint4*)((char*)sampled + (size_t)m*512 + laneoff) = outv;
}

// ---------------------------------------------------------------- residual + LN
template<bool WRITE_QPB>
__global__ __launch_bounds__(256) void ln_kernel(
    bf16* __restrict__ qb, const bf16* __restrict__ delta,
    const float* __restrict__ g, const float* __restrict__ be,
    const bf16* __restrict__ qpos, bf16* __restrict__ qpb, float* __restrict__ dout)
{
    const int wv = threadIdx.x >> 6, lane = threadIdx.x & 63;
    const size_t o = ((size_t)blockIdx.x*4 + wv)*256 + lane*4;
    ushort4 qv = *(const ushort4*)&qb[o];
    ushort4 dv = *(const ushort4*)&delta[o];
    float x0 = bfu(qv.x) + bfu(dv.x);
    float x1 = bfu(qv.y) + bfu(dv.y);
    float x2 = bfu(qv.z) + bfu(dv.z);
    float x3 = bfu(qv.w) + bfu(dv.w);
    float s1 = x0+x1+x2+x3;
    float s2 = x0*x0+x1*x1+x2*x2+x3*x3;
#pragma unroll
    for (int i=1;i<64;i<<=1){ s1 += __shfl_xor(s1,i); s2 += __shfl_xor(s2,i); }
    float mu  = s1 * (1.f/256.f);
    float var = s2 * (1.f/256.f) - mu*mu;
    float rs  = rsqrtf(var + 1e-5f);
    float4 gv = *(const float4*)&g[lane*4];
    float4 bv = *(const float4*)&be[lane*4];
    float y0 = (x0-mu)*rs*gv.x + bv.x;
    float y1 = (x1-mu)*rs*gv.y + bv.y;
    float y2 = (x2-mu)*rs*gv.z + bv.z;
    float y3 = (x3-mu)*rs*gv.w + bv.w;
    ushort4 qo; qo.x=f2b(y0); qo.y=f2b(y1); qo.z=f2b(y2); qo.w=f2b(y3);
    *(ushort4*)&qb[o] = qo;
    if constexpr (WRITE_QPB) {
        ushort4 pv = *(const ushort4*)&qpos[o];
        ushort4 po;
        po.x = f2b(y0 + bfu(pv.x));
        po.y = f2b(y1 + bfu(pv.y));
        po.z = f2b(y2 + bfu(pv.z));
        po.w = f2b(y3 + bfu(pv.w));
        *(ushort4*)&qpb[o] = po;
    }
    if (dout) { *(float4*)&dout[o] = make_float4(y0,y1,y2,y3); }
}

// ---------------------------------------------------------------- launch
extern "C" void kernel_launch(void* const* d_in, const int* in_sizes, int n_in,
                              void* d_out, int out_size, void* d_ws, size_t ws_size,
                              hipStream_t stream)
{
    // setup_inputs() dict order is INTERLEAVED: src0,pos0,src1,pos1,...
    const float* src0 = (const float*)d_in[0];
    const float* pos0 = (const float*)d_in[1];
    const float* src1 = (const float*)d_in[2];
    const float* pos1 = (const float*)d_in[3];
    const float* src2 = (const float*)d_in[4];
    const float* pos2 = (const float*)d_in[5];
    const float* src3 = (const float*)d_in[6];
    const float* pos3 = (const float*)d_in[7];
    const float* le   = (const float*)d_in[8];
    const float* Wv   = (const float*)d_in[9];
    const float* bv   = (const float*)d_in[10];
    const float* Ws   = (const float*)d_in[11];
    const float* bso  = (const float*)d_in[12];
    const float* Wa   = (const float*)d_in[13];
    const float* ba   = (const float*)d_in[14];
    const float* Wo   = (const float*)d_in[15];
    const float* bo   = (const float*)d_in[16];
    const float* g1   = (const float*)d_in[17];
    const float* be1  = (const float*)d_in[18];
    const float* W1   = (const float*)d_in[19];
    const float* b1   = (const float*)d_in[20];
    const float* W2   = (const float*)d_in[21];
    const float* b2   = (const float*)d_in[22];
    const float* g2   = (const float*)d_in[23];
    const float* be2  = (const float*)d_in[24];

    if (ws_size < WS_NEED) {   // diagnostic: absmax ~1e6 means ws too small
        sentinel_kernel<<<1, 1, 0, stream>>>((float*)d_out);
        return;
    }
    char* ws = (char*)d_ws;
    bf16*  qpos   = (bf16*) (ws + OFF_QPOS);
    bf16*  qb     = (bf16*) (ws + OFF_QB);
    bf16*  qpb    = (bf16*) (ws + OFF_QPB);
    bf16*  sampled= (bf16*) (ws + OFF_QPB);   // alias: qpb dead after gemm0
    bf16*  delta2 = (bf16*) (ws + OFF_QPB);   // FFN out; ln2 reads then writes qpb in place
    bf16*  wp     = (bf16*) (ws + OFF_WP);
    float* bp     = (float*)(ws + OFF_BP);
    float* offb   = (float*)(ws + OFF_R1);    // gemm0 -> sample
    bf16*  hidden = (bf16*) (ws + OFF_R1);    // FFN: spans R1+VAL+AW (89.13 MB, exact)
    bf16*  value  = (bf16*) (ws + OFF_VAL);   // gemm0 -> sample
    bf16*  delta1 = (bf16*) (ws + OFF_VAL);   // gemm1 -> ln1 (value dead by then)
    float* awb    = (float*)(ws + OFF_AW);

    pack_kernel<<<dim3(4096), 256, 0, stream>>>(Wv, Ws, Wa, Wo, W1, W2, bv, bso, ba, wp, bp);
    prep_pos_kernel<<<dim3(340,8,2), 256, 0, stream>>>(pos0,pos1,pos2,pos3, le, qpos);
    prep_q_kernel<<<dim3(340,8,2), 256, 0, stream>>>(src0,src1,src2,src3, qpos, qb, qpb);

    for (int l = 0; l < NLAY; ++l) {
        const bf16* wl_ = wp + (size_t)l*PER_L;
        gemm_kernel<0><<<dim3(340,5), 256, 0, stream>>>(qb, qpb, wl_, bp + l*640, 256,
                                                        value, offb, awb);
        sample_kernel<<<dim3(M_TOT/8), 256, 0, stream>>>(value, offb, awb, sampled);
        gemm_kernel<1><<<dim3(340,2), 256, 0, stream>>>(sampled, nullptr, wl_ + WVSA_SZ,
                                                        bo + l*256, 256, delta1, nullptr, nullptr);
        ln_kernel<false><<<dim3(M_TOT/4), 256, 0, stream>>>(qb, delta1, g1 + l*256, be1 + l*256,
                                                            nullptr, nullptr, nullptr);
        gemm_kernel<2><<<dim3(340,8), 256, 0, stream>>>(qb, nullptr, wl_ + WVSA_SZ + WO_SZ,
                                                        b1 + l*1024, 256, hidden, nullptr, nullptr);
        gemm_kernel<1><<<dim3(340,2), 256, 0, stream>>>(hidden, nullptr,
                                                        wl_ + WVSA_SZ + WO_SZ + W1_SZ,
                                                        b2 + l*256, 1024, delta2, nullptr, nullptr);
        ln_kernel<true><<<dim3(M_TOT/4), 256, 0, stream>>>(qb, delta2, g2 + l*256, be2 + l*256,
                                                           qpos, qpb, (l==NLAY-1) ? (float*)d_out : nullptr);
    }
}

// Round 14
// 1512.929 us; speedup vs baseline: 1.0911x; 1.0005x over previous
//
#include <hip/hip_runtime.h>
#include <hip/hip_bf16.h>
#include <stdint.h>

#define D_MODEL 256
#define N_TOK   21760
#define BATCH   2
#define M_TOT   (BATCH*N_TOK)   // 43520 = 340*128
#define NLAY    6

typedef __hip_bfloat16 bf16;
typedef short bf16x8 __attribute__((ext_vector_type(8)));
typedef float f32x4  __attribute__((ext_vector_type(4)));

// packed per-layer weight block (bf16, transposed to [N][K])
#define WVSA_SZ (640*256)
#define WO_SZ   (256*256)
#define W1_SZ   (1024*256)
#define W2_SZ   (256*1024)
#define PER_L   (WVSA_SZ+WO_SZ+W1_SZ+W2_SZ)  // 753664

// ---- workspace layout (aliased by lifetime), total ~165.4 MB ----
#define SZ_QF   ((size_t)M_TOT*256*4)
#define SZ_BF   ((size_t)M_TOT*256*2)
#define SZ_AW   ((size_t)M_TOT*128*4)
#define SZ_WP   ((size_t)PER_L*NLAY*2)
#define SZ_BP   ((size_t)NLAY*640*4)
#define OFF_QPOS  ((size_t)0)
#define OFF_QB    (OFF_QPOS + SZ_BF)
#define OFF_QPB   (OFF_QB   + SZ_BF)    // sampled | delta2
#define OFF_WP    (OFF_QPB  + SZ_BF)
#define OFF_BP    (OFF_WP   + SZ_WP)
#define OFF_R1    (OFF_BP   + SZ_BP)    // offb f32 | hidden (spans R1+VAL+AW)
#define OFF_VAL   (OFF_R1   + SZ_QF)    // value bf16 | delta1 bf16
#define OFF_AW    (OFF_VAL  + SZ_BF)
#define WS_NEED   (OFF_AW   + SZ_AW)

// ---------------------------------------------------------------- helpers
typedef const __attribute__((address_space(1))) void gvoid_t;
typedef __attribute__((address_space(3))) void lvoid_t;
__device__ __forceinline__ void gload_lds16(const void* g, void* l){
    __builtin_amdgcn_global_load_lds((gvoid_t*)g, (lvoid_t*)l, 16, 0, 0);
}
__device__ __forceinline__ float bfu(ushort u){ return __uint_as_float(((uint)u)<<16); }
__device__ __forceinline__ ushort f2b(float f){ return __bfloat16_as_ushort(__float2bfloat16(f)); }
__device__ __forceinline__ float bf16_lo(uint u){ return __uint_as_float(u << 16); }
__device__ __forceinline__ float bf16_hi(uint u){ return __uint_as_float(u & 0xffff0000u); }

// ---------------------------------------------------------------- sentinel
__global__ void sentinel_kernel(float* out) { out[0] = 1.0e6f; }

// ---------------------------------------------------------------- pack
__global__ void pack_kernel(const float* __restrict__ Wv, const float* __restrict__ Ws,
                            const float* __restrict__ Wa, const float* __restrict__ Wo,
                            const float* __restrict__ W1, const float* __restrict__ W2,
                            const float* __restrict__ bv, const float* __restrict__ bso,
                            const float* __restrict__ ba,
                            bf16* __restrict__ wp, float* __restrict__ bp)
{
    const int WTOT = PER_L * NLAY;
    for (int idx = blockIdx.x*blockDim.x + threadIdx.x; idx < WTOT + NLAY*640;
         idx += gridDim.x*blockDim.x) {
        if (idx < WTOT) {
            int l = idx / PER_L, r = idx - l*PER_L;
            float v;
            if (r < WVSA_SZ) {                       // Wvsa_t[640][256]
                int n = r >> 8, k = r & 255;
                if (n < 256)      v = Wv[((size_t)l*256+k)*256 + n];
                else if (n < 512) v = Ws[((size_t)l*256+k)*256 + (n-256)];
                else              v = Wa[((size_t)l*256+k)*128 + (n-512)];
            } else if (r < WVSA_SZ+WO_SZ) {          // Wo_t[256][256]
                int j = r - WVSA_SZ; int n = j >> 8, k = j & 255;
                v = Wo[((size_t)l*256+k)*256 + n];
            } else if (r < WVSA_SZ+WO_SZ+W1_SZ) {    // W1_t[1024][256]
                int j = r - (WVSA_SZ+WO_SZ); int n = j >> 8, k = j & 255;
                v = W1[((size_t)l*256+k)*1024 + n];
            } else {                                 // W2_t[256][1024]
                int j = r - (WVSA_SZ+WO_SZ+W1_SZ); int n = j >> 10, k = j & 1023;
                v = W2[((size_t)l*1024+k)*256 + n];
            }
            wp[idx] = __float2bfloat16(v);
        } else {
            int i = idx - WTOT; int l = i / 640, n = i - l*640;
            float v = (n < 256) ? bv[l*256+n]
                    : (n < 512) ? bso[l*256+(n-256)]
                                : ba[l*128+(n-512)];
            bp[l*640+n] = v;
        }
    }
}

// ---------------------------------------------------------------- prep (src transpose)
__device__ __forceinline__ void tile_decode(int st, int& lvl, int& s0, int& hw, int& start)
{
    if (st < 256)      { lvl=0; s0=st*64;       hw=16384; start=0; }
    else if (st < 320) { lvl=1; s0=(st-256)*64; hw=4096;  start=16384; }
    else if (st < 336) { lvl=2; s0=(st-320)*64; hw=1024;  start=20480; }
    else               { lvl=3; s0=(st-336)*64; hw=256;   start=21504; }
}

__global__ __launch_bounds__(256) void prep_pos_kernel(
    const float* __restrict__ p0, const float* __restrict__ p1,
    const float* __restrict__ p2, const float* __restrict__ p3,
    const float* __restrict__ le, bf16* __restrict__ qpos)
{
    __shared__ float tile[32][65];
    int lvl, s0, hw, start; tile_decode(blockIdx.x, lvl, s0, hw, start);
    const float* sp = lvl==0?p0 : lvl==1?p1 : lvl==2?p2 : p3;
    const int t = threadIdx.x, b = blockIdx.z, c0 = blockIdx.y*32;
#pragma unroll
    for (int j=0;j<8;++j){
        int cl = j*4 + (t>>6), sl = t&63;
        tile[cl][sl] = sp[((size_t)b*256 + c0+cl)*hw + s0 + sl];
    }
    __syncthreads();
#pragma unroll
    for (int j=0;j<8;++j){
        int sl = j*8 + (t>>5), cl = t&31;
        float v = tile[cl][sl] + le[lvl*256 + c0 + cl];
        size_t o = ((size_t)b*N_TOK + start + s0 + sl)*256 + c0 + cl;
        qpos[o] = __float2bfloat16(v);
    }
}

__global__ __launch_bounds__(256) void prep_q_kernel(
    const float* __restrict__ s0p, const float* __restrict__ s1p,
    const float* __restrict__ s2p, const float* __restrict__ s3p,
    const bf16* __restrict__ qpos,
    bf16* __restrict__ qb, bf16* __restrict__ qpb)
{
    __shared__ float tile[32][65];
    int lvl, s0, hw, start; tile_decode(blockIdx.x, lvl, s0, hw, start);
    const float* sp = lvl==0?s0p : lvl==1?s1p : lvl==2?s2p : s3p;
    const int t = threadIdx.x, b = blockIdx.z, c0 = blockIdx.y*32;
#pragma unroll
    for (int j=0;j<8;++j){
        int cl = j*4 + (t>>6), sl = t&63;
        tile[cl][sl] = sp[((size_t)b*256 + c0+cl)*hw + s0 + sl];
    }
    __syncthreads();
#pragma unroll
    for (int j=0;j<8;++j){
        int sl = j*8 + (t>>5), cl = t&31;
        float v = tile[cl][sl];
        size_t o = ((size_t)b*N_TOK + start + s0 + sl)*256 + c0 + cl;
        qb[o] = __float2bfloat16(v);
        qpb[o] = __float2bfloat16(v + __bfloat162float(qpos[o]));
    }
}

// ---------------------------------------------------------------- GEMM (bf16 MFMA)
// 128x128 tile, 4 waves 2x2 (round-11 config). Double-buffered 2-phase pipeline.
template<int MODE>
__global__ __launch_bounds__(256) void gemm_kernel(
    const bf16* __restrict__ A, const bf16* __restrict__ A2,
    const bf16* __restrict__ Wt, const float* __restrict__ bias,
    int K, void* __restrict__ out0, void* __restrict__ out1, void* __restrict__ out2)
{
    __shared__ __align__(1024) ushort As[2][128*32];
    __shared__ __align__(1024) ushort Bs[2][128*32];
    const int tid = threadIdx.x;
    const int lane = tid & 63, w = tid >> 6;
    const int wr = w >> 1, wc = w & 1;
    const int lr = lane & 15, lg = lane >> 4;
    const size_t m0 = (size_t)blockIdx.x * 128;
    const int n0 = blockIdx.y * 128;
    const bf16* Ause = (MODE == 0 && n0 >= 256) ? A2 : A;

    const int srow0 = (w<<5) + (lane>>2);
    const int sphys = (lane&3);
    const int KSTEPS = K >> 5;

    auto stage = [&](int ks, int buf){
        const int k0 = ks*32;
#pragma unroll
        for (int j=0;j<2;++j){
            int row  = srow0 + j*16;
            int slot = sphys ^ ((row>>1)&3);  // pre-swizzled global source
            gload_lds16(&Ause[(m0+row)*(size_t)K + k0 + slot*8], &As[buf][row*32 + sphys*8]);
            gload_lds16(&Wt[(size_t)(n0+row)*K + k0 + slot*8],   &Bs[buf][row*32 + sphys*8]);
        }
    };

    f32x4 acc[4][4];
#pragma unroll
    for (int i=0;i<4;++i)
#pragma unroll
        for (int j=0;j<4;++j) acc[i][j] = (f32x4){0.f,0.f,0.f,0.f};

    stage(0, 0);
    for (int ks = 0; ks < KSTEPS; ++ks) {
        const int cur = ks & 1;
        if (ks + 1 < KSTEPS) {
            stage(ks + 1, cur ^ 1);
            asm volatile("s_waitcnt vmcnt(4)" ::: "memory");
        } else {
            asm volatile("s_waitcnt vmcnt(0)" ::: "memory");
        }
        __builtin_amdgcn_s_barrier();
        bf16x8 av[4], bw[4];
#pragma unroll
        for (int i=0;i<4;++i){
            int ar = wr*64 + i*16 + lr;
            int br = wc*64 + i*16 + lr;
            av[i] = *(bf16x8*)&As[cur][ar*32 + ((lg ^ ((ar>>1)&3))<<3)];
            bw[i] = *(bf16x8*)&Bs[cur][br*32 + ((lg ^ ((br>>1)&3))<<3)];
        }
#pragma unroll
        for (int mi=0;mi<4;++mi)
#pragma unroll
            for (int ni=0;ni<4;++ni)
                acc[mi][ni] = __builtin_amdgcn_mfma_f32_16x16x32_bf16(av[mi], bw[ni], acc[mi][ni], 0,0,0);
        asm volatile("s_waitcnt lgkmcnt(0)" ::: "memory");
        __builtin_amdgcn_sched_barrier(0);
        __builtin_amdgcn_s_barrier();
    }
#pragma unroll
    for (int mi=0;mi<4;++mi){
#pragma unroll
        for (int ni=0;ni<4;++ni){
            int gr0 = (int)m0 + wr*64 + mi*16 + lg*4;
            int gc  = n0 + wc*64 + ni*16 + lr;
            float bb = bias[gc];
#pragma unroll
            for (int r=0;r<4;++r){
                float y = acc[mi][ni][r] + bb;
                size_t row = (size_t)(gr0 + r);
                if (MODE == 0) {
                    if (gc < 256)      ((bf16*)out0)[row*256 + gc] = __float2bfloat16(y);
                    else if (gc < 512) ((float*)out1)[row*256 + (gc-256)] = y;
                    else               ((float*)out2)[row*128 + (gc-512)] = y;
                } else if (MODE == 1) {
                    ((bf16*)out0)[row*256 + gc] = __float2bfloat16(y);
                } else {
                    ((bf16*)out0)[row*1024 + gc] = __float2bfloat16(fmaxf(y, 0.f));
                }
            }
        }
    }
}

// ---------------------------------------------------------------- deformable sampling
// One wave per 2 tokens: lane = t*32 + h*4 + c; each lane gathers uint4 (16B).
// LDS table compressed to 20 B/slot: f32x4 weights + ONE packed int
// (o00 | xflag | yflag<<1; o00 is x512 so low 9 bits free). Tap addresses are
// reconstructed as o00 + xflag*512 + yflag*(65536>>lvl) -- reproduces the
// clamp-adjusted addresses exactly (flag = cx1>cx0 / cy1>cy0).
// 21760 B LDS -> 7 blocks/CU (vs 4 with the 32 B/slot layout).
__global__ __launch_bounds__(256) void sample_kernel(
    const bf16* __restrict__ value, const float* __restrict__ offb,
    const float* __restrict__ awb, bf16* __restrict__ sampled)
{
    __shared__ float tabw[8][136][4];
    __shared__ int   tabo[8][136];
    const int nb = gridDim.x;                 // 5440, % 8 == 0
    const int chunk = nb >> 3;
    const int bid = (blockIdx.x & 7) * chunk + (blockIdx.x >> 3);
    const int wv = threadIdx.x >> 6, lane = threadIdx.x & 63;
    const int t = lane >> 5, L = lane & 31;
    const int tt = wv*2 + t;                  // token slot in block (0..7)
    const int m = bid*8 + tt;

    const int b = m / N_TOK;                  // uniform per block (21760 % 8 == 0)
    const int n = m - b*N_TOK;
    float refx, refy;
    if (n < 16384)      { int s=n;       int qy=s>>7, qx=s&127; refx=(qx+0.5f)*(1.f/128.f); refy=(qy+0.5f)*(1.f/128.f); }
    else if (n < 20480) { int s=n-16384; int qy=s>>6, qx=s&63;  refx=(qx+0.5f)*(1.f/64.f);  refy=(qy+0.5f)*(1.f/64.f); }
    else if (n < 21504) { int s=n-20480; int qy=s>>5, qx=s&31;  refx=(qx+0.5f)*(1.f/32.f);  refy=(qy+0.5f)*(1.f/32.f); }
    else                { int s=n-21504; int qy=s>>4, qx=s&15;  refx=(qx+0.5f)*(1.f/16.f);  refy=(qy+0.5f)*(1.f/16.f); }

    // softmax: 4 logits/lane; head group = 4 lanes (xor 1,2 stays in group)
    float4 lg = *(const float4*)&awb[(size_t)m*128 + L*4];
    float mx = fmaxf(fmaxf(lg.x,lg.y), fmaxf(lg.z,lg.w));
    mx = fmaxf(mx, __shfl_xor(mx,1));
    mx = fmaxf(mx, __shfl_xor(mx,2));
    float e0=__expf(lg.x-mx), e1=__expf(lg.y-mx), e2=__expf(lg.z-mx), e3=__expf(lg.w-mx);
    float sm = e0+e1+e2+e3;
    sm += __shfl_xor(sm,1);
    sm += __shfl_xor(sm,2);
    float rs = __frcp_rn(sm);
    float wgt[4] = {e0*rs, e1*rs, e2*rs, e3*rs};

    // offsets: 8 floats/lane = points 4L..4L+3
    float4 oA = *(const float4*)&offb[(size_t)m*256 + L*8];
    float4 oB = *(const float4*)&offb[(size_t)m*256 + L*8 + 4];
    float offx[4] = {oA.x, oA.z, oB.x, oB.z};
    float offy[4] = {oA.y, oA.w, oB.y, oB.w};

    const int LSTART[4] = {0, 16384, 20480, 21504};
#pragma unroll
    for (int j=0;j<4;++j){
        int pg  = L*4 + j;
        int lvl = (pg >> 2) & 3;
        int wl  = 128 >> lvl;
        float fx = refx*(float)wl - 0.5f + offx[j];
        float fy = refy*(float)wl - 0.5f + offy[j];
        float x0f = floorf(fx), y0f = floorf(fy);
        float dx = fx - x0f, dy = fy - y0f;
        int ix = (int)x0f, iy = (int)y0f;
        int cx0 = min(max(ix,0),   wl-1), cx1 = min(max(ix+1,0), wl-1);
        int cy0 = min(max(iy,0),   wl-1), cy1 = min(max(iy+1,0), wl-1);
        bool vx0 = (unsigned)ix     < (unsigned)wl, vx1 = (unsigned)(ix+1) < (unsigned)wl;
        bool vy0 = (unsigned)iy     < (unsigned)wl, vy1 = (unsigned)(iy+1) < (unsigned)wl;
        float a = 1.f-dx, bb = 1.f-dy;
        int slot = (pg >> 4)*17 + (pg & 15);
        float4 wq;
        wq.x = (vx0&&vy0) ? a*bb*wgt[j] : 0.f;
        wq.y = (vx1&&vy0) ? dx*bb*wgt[j] : 0.f;
        wq.z = (vx0&&vy1) ? a*dy*wgt[j] : 0.f;
        wq.w = (vx1&&vy1) ? dx*dy*wgt[j] : 0.f;
        *(float4*)&tabw[tt][slot][0] = wq;
        int lb = LSTART[lvl];
        int o00 = (lb + cy0*wl + cx0) << 9;
        tabo[tt][slot] = o00 | (cx1 > cx0 ? 1 : 0) | (cy1 > cy0 ? 2 : 0);
    }
    __syncthreads();

    const int h = (lane >> 2) & 7, c = lane & 3;
    const int rb = __builtin_amdgcn_readfirstlane(b);
    const char* vb = (const char*)value + (size_t)rb*N_TOK*512;
    const int laneoff = h*64 + c*16;          // byte offset of 8-channel group
    f32x4 accA = (f32x4){0.f,0.f,0.f,0.f};
    f32x4 accB = (f32x4){0.f,0.f,0.f,0.f};
#pragma unroll 4
    for (int k=0;k<16;++k){
        int slot = h*17 + k;
        float4 w  = *(const float4*)&tabw[tt][slot][0];
        int    io = tabo[tt][slot];
        int o00 = (io & ~511) + laneoff;
        int dxo = (io & 1) << 9;
        int dyo = (io & 2) ? (65536 >> (k >> 2)) : 0;
        uint4 q00 = *(const uint4*)(vb + o00);
        uint4 q01 = *(const uint4*)(vb + (o00 + dxo));
        uint4 q10 = *(const uint4*)(vb + (o00 + dyo));
        uint4 q11 = *(const uint4*)(vb + (o00 + dxo + dyo));
        accA[0] += w.x*bf16_lo(q00.x) + w.y*bf16_lo(q01.x) + w.z*bf16_lo(q10.x) + w.w*bf16_lo(q11.x);
        accA[1] += w.x*bf16_hi(q00.x) + w.y*bf16_hi(q01.x) + w.z*bf16_hi(q10.x) + w.w*bf16_hi(q11.x);
        accA[2] += w.x*bf16_lo(q00.y) + w.y*bf16_lo(q01.y) + w.z*bf16_lo(q10.y) + w.w*bf16_lo(q11.y);
        accA[3] += w.x*bf16_hi(q00.y) + w.y*bf16_hi(q01.y) + w.z*bf16_hi(q10.y) + w.w*bf16_hi(q11.y);
        accB[0] += w.x*bf16_lo(q00.z) + w.y*bf16_lo(q01.z) + w.z*bf16_lo(q10.z) + w.w*bf16_lo(q11.z);
        accB[1] += w.x*bf16_hi(q00.z) + w.y*bf16_hi(q01.z) + w.z*bf16_hi(q10.z) + w.w*bf16_hi(q11.z);
        accB[2] += w.x*bf16_lo(q00.w) + w.y*bf16_lo(q01.w) + w.z*bf16_lo(q10.w) + w.w*bf16_lo(q11.w);
        accB[3] += w.x*bf16_hi(q00.w) + w.y*bf16_hi(q01.w) + w.z*bf16_hi(q10.w) + w.w*bf16_hi(q11.w);
    }
    uint4 outv;
    outv.x = (uint)f2b(accA[0]) | ((uint)f2b(accA[1])<<16);
    outv.y = (uint)f2b(accA[2]) | ((uint)f2b(accA[3])<<16);
    outv.z = (uint)f2b(accB[0]) | ((uint)f2b(accB[1])<<16);
    outv.w = (uint)f2b(accB[2]) | ((uint)f2b(accB[3])<<16);
    *(uint4*)((char*)sampled + (size_t)m*512 + laneoff) = outv;
}

// ---------------------------------------------------------------- residual + LN
template<bool WRITE_QPB>
__global__ __launch_bounds__(256) void ln_kernel(
    bf16* __restrict__ qb, const bf16* __restrict__ delta,
    const float* __restrict__ g, const float* __restrict__ be,
    const bf16* __restrict__ qpos, bf16* __restrict__ qpb, float* __restrict__ dout)
{
    const int wv = threadIdx.x >> 6, lane = threadIdx.x & 63;
    const size_t o = ((size_t)blockIdx.x*4 + wv)*256 + lane*4;
    ushort4 qv = *(const ushort4*)&qb[o];
    ushort4 dv = *(const ushort4*)&delta[o];
    float x0 = bfu(qv.x) + bfu(dv.x);
    float x1 = bfu(qv.y) + bfu(dv.y);
    float x2 = bfu(qv.z) + bfu(dv.z);
    float x3 = bfu(qv.w) + bfu(dv.w);
    float s1 = x0+x1+x2+x3;
    float s2 = x0*x0+x1*x1+x2*x2+x3*x3;
#pragma unroll
    for (int i=1;i<64;i<<=1){ s1 += __shfl_xor(s1,i); s2 += __shfl_xor(s2,i); }
    float mu  = s1 * (1.f/256.f);
    float var = s2 * (1.f/256.f) - mu*mu;
    float rs  = rsqrtf(var + 1e-5f);
    float4 gv = *(const float4*)&g[lane*4];
    float4 bv = *(const float4*)&be[lane*4];
    float y0 = (x0-mu)*rs*gv.x + bv.x;
    float y1 = (x1-mu)*rs*gv.y + bv.y;
    float y2 = (x2-mu)*rs*gv.z + bv.z;
    float y3 = (x3-mu)*rs*gv.w + bv.w;
    ushort4 qo; qo.x=f2b(y0); qo.y=f2b(y1); qo.z=f2b(y2); qo.w=f2b(y3);
    *(ushort4*)&qb[o] = qo;
    if constexpr (WRITE_QPB) {
        ushort4 pv = *(const ushort4*)&qpos[o];
        ushort4 po;
        po.x = f2b(y0 + bfu(pv.x));
        po.y = f2b(y1 + bfu(pv.y));
        po.z = f2b(y2 + bfu(pv.z));
        po.w = f2b(y3 + bfu(pv.w));
        *(ushort4*)&qpb[o] = po;
    }
    if (dout) { *(float4*)&dout[o] = make_float4(y0,y1,y2,y3); }
}

// ---------------------------------------------------------------- launch
extern "C" void kernel_launch(void* const* d_in, const int* in_sizes, int n_in,
                              void* d_out, int out_size, void* d_ws, size_t ws_size,
                              hipStream_t stream)
{
    // setup_inputs() dict order is INTERLEAVED: src0,pos0,src1,pos1,...
    const float* src0 = (const float*)d_in[0];
    const float* pos0 = (const float*)d_in[1];
    const float* src1 = (const float*)d_in[2];
    const float* pos1 = (const float*)d_in[3];
    const float* src2 = (const float*)d_in[4];
    const float* pos2 = (const float*)d_in[5];
    const float* src3 = (const float*)d_in[6];
    const float* pos3 = (const float*)d_in[7];
    const float* le   = (const float*)d_in[8];
    const float* Wv   = (const float*)d_in[9];
    const float* bv   = (const float*)d_in[10];
    const float* Ws   = (const float*)d_in[11];
    const float* bso  = (const float*)d_in[12];
    const float* Wa   = (const float*)d_in[13];
    const float* ba   = (const float*)d_in[14];
    const float* Wo   = (const float*)d_in[15];
    const float* bo   = (const float*)d_in[16];
    const float* g1   = (const float*)d_in[17];
    const float* be1  = (const float*)d_in[18];
    const float* W1   = (const float*)d_in[19];
    const float* b1   = (const float*)d_in[20];
    const float* W2   = (const float*)d_in[21];
    const float* b2   = (const float*)d_in[22];
    const float* g2   = (const float*)d_in[23];
    const float* be2  = (const float*)d_in[24];

    if (ws_size < WS_NEED) {   // diagnostic: absmax ~1e6 means ws too small
        sentinel_kernel<<<1, 1, 0, stream>>>((float*)d_out);
        return;
    }
    char* ws = (char*)d_ws;
    bf16*  qpos   = (bf16*) (ws + OFF_QPOS);
    bf16*  qb     = (bf16*) (ws + OFF_QB);
    bf16*  qpb    = (bf16*) (ws + OFF_QPB);
    bf16*  sampled= (bf16*) (ws + OFF_QPB);   // alias: qpb dead after gemm0
    bf16*  delta2 = (bf16*) (ws + OFF_QPB);   // FFN out; ln2 reads then writes qpb in place
    bf16*  wp     = (bf16*) (ws + OFF_WP);
    float* bp     = (float*)(ws + OFF_BP);
    float* offb   = (float*)(ws + OFF_R1);    // gemm0 -> sample
    bf16*  hidden = (bf16*) (ws + OFF_R1);    // FFN: spans R1+VAL+AW (89.13 MB, exact)
    bf16*  value  = (bf16*) (ws + OFF_VAL);   // gemm0 -> sample
    bf16*  delta1 = (bf16*) (ws + OFF_VAL);   // gemm1 -> ln1 (value dead by then)
    float* awb    = (float*)(ws + OFF_AW);

    pack_kernel<<<dim3(4096), 256, 0, stream>>>(Wv, Ws, Wa, Wo, W1, W2, bv, bso, ba, wp, bp);
    prep_pos_kernel<<<dim3(340,8,2), 256, 0, stream>>>(pos0,pos1,pos2,pos3, le, qpos);
    prep_q_kernel<<<dim3(340,8,2), 256, 0, stream>>>(src0,src1,src2,src3, qpos, qb, qpb);

    for (int l = 0; l < NLAY; ++l) {
        const bf16* wl_ = wp + (size_t)l*PER_L;
        gemm_kernel<0><<<dim3(340,5), 256, 0, stream>>>(qb, qpb, wl_, bp + l*640, 256,
                                                        value, offb, awb);
        sample_kernel<<<dim3(M_TOT/8), 256, 0, stream>>>(value, offb, awb, sampled);
        gemm_kernel<1><<<dim3(340,2), 256, 0, stream>>>(sampled, nullptr, wl_ + WVSA_SZ,
                                                        bo + l*256, 256, delta1, nullptr, nullptr);
        ln_kernel<false><<<dim3(M_TOT/4), 256, 0, stream>>>(qb, delta1, g1 + l*256, be1 + l*256,
                                                            nullptr, nullptr, nullptr);
        gemm_kernel<2><<<dim3(340,8), 256, 0, stream>>>(qb, nullptr, wl_ + WVSA_SZ + WO_SZ,
                                                        b1 + l*1024, 256, hidden, nullptr, nullptr);
        gemm_kernel<1><<<dim3(340,2), 256, 0, stream>>>(hidden, nullptr,
                                                        wl_ + WVSA_SZ + WO_SZ + W1_SZ,
                                                        b2 + l*256, 1024, delta2, nullptr, nullptr);
        ln_kernel<true><<<dim3(M_TOT/4), 256, 0, stream>>>(qb, delta2, g2 + l*256, be2 + l*256,
                                                           qpos, qpb, (l==NLAY-1) ? (float*)d_out : nullptr);
    }
}

// Round 15
// 1477.581 us; speedup vs baseline: 1.1172x; 1.0239x over previous
//
#include <hip/hip_runtime.h>
#include <hip/hip_bf16.h>
#include <stdint.h>

#define D_MODEL 256
#define N_TOK   21760
#define BATCH   2
#define M_TOT   (BATCH*N_TOK)   // 43520 = 340*128
#define NLAY    6

typedef __hip_bfloat16 bf16;
typedef short bf16x8 __attribute__((ext_vector_type(8)));
typedef float f32x4  __attribute__((ext_vector_type(4)));

// packed per-layer weight block (bf16, transposed to [N][K])
#define WVSA_SZ (640*256)
#define WO_SZ   (256*256)
#define W1_SZ   (1024*256)
#define W2_SZ   (256*1024)
#define PER_L   (WVSA_SZ+WO_SZ+W1_SZ+W2_SZ)  // 753664

// ---- workspace layout (aliased by lifetime) ----
#define SZ_QF   ((size_t)M_TOT*256*4)
#define SZ_BF   ((size_t)M_TOT*256*2)
#define SZ_AW   ((size_t)M_TOT*128*4)
#define SZ_WP   ((size_t)PER_L*NLAY*2)
#define SZ_BP   ((size_t)NLAY*640*4)
#define OFF_QPOS  ((size_t)0)
#define OFF_QB    (OFF_QPOS + SZ_BF)
#define OFF_QPB   (OFF_QB   + SZ_BF)    // sampled | delta2
#define OFF_WP    (OFF_QPB  + SZ_BF)
#define OFF_BP    (OFF_WP   + SZ_WP)
#define OFF_R1    (OFF_BP   + SZ_BP)    // offb bf16 | hidden (spans R1+VAL+AW)
#define OFF_VAL   (OFF_R1   + SZ_QF)    // value bf16 | delta1 bf16
#define OFF_AW    (OFF_VAL  + SZ_BF)    // awb bf16
#define WS_NEED   (OFF_AW   + SZ_AW)

// ---------------------------------------------------------------- helpers
typedef const __attribute__((address_space(1))) void gvoid_t;
typedef __attribute__((address_space(3))) void lvoid_t;
__device__ __forceinline__ void gload_lds16(const void* g, void* l){
    __builtin_amdgcn_global_load_lds((gvoid_t*)g, (lvoid_t*)l, 16, 0, 0);
}
__device__ __forceinline__ float bfu(ushort u){ return __uint_as_float(((uint)u)<<16); }
__device__ __forceinline__ ushort f2b(float f){ return __bfloat16_as_ushort(__float2bfloat16(f)); }
__device__ __forceinline__ float bf16_lo(uint u){ return __uint_as_float(u << 16); }
__device__ __forceinline__ float bf16_hi(uint u){ return __uint_as_float(u & 0xffff0000u); }

// ---------------------------------------------------------------- sentinel
__global__ void sentinel_kernel(float* out) { out[0] = 1.0e6f; }

// ---------------------------------------------------------------- pack
__global__ void pack_kernel(const float* __restrict__ Wv, const float* __restrict__ Ws,
                            const float* __restrict__ Wa, const float* __restrict__ Wo,
                            const float* __restrict__ W1, const float* __restrict__ W2,
                            const float* __restrict__ bv, const float* __restrict__ bso,
                            const float* __restrict__ ba,
                            bf16* __restrict__ wp, float* __restrict__ bp)
{
    const int WTOT = PER_L * NLAY;
    for (int idx = blockIdx.x*blockDim.x + threadIdx.x; idx < WTOT + NLAY*640;
         idx += gridDim.x*blockDim.x) {
        if (idx < WTOT) {
            int l = idx / PER_L, r = idx - l*PER_L;
            float v;
            if (r < WVSA_SZ) {                       // Wvsa_t[640][256]
                int n = r >> 8, k = r & 255;
                if (n < 256)      v = Wv[((size_t)l*256+k)*256 + n];
                else if (n < 512) v = Ws[((size_t)l*256+k)*256 + (n-256)];
                else              v = Wa[((size_t)l*256+k)*128 + (n-512)];
            } else if (r < WVSA_SZ+WO_SZ) {          // Wo_t[256][256]
                int j = r - WVSA_SZ; int n = j >> 8, k = j & 255;
                v = Wo[((size_t)l*256+k)*256 + n];
            } else if (r < WVSA_SZ+WO_SZ+W1_SZ) {    // W1_t[1024][256]
                int j = r - (WVSA_SZ+WO_SZ); int n = j >> 8, k = j & 255;
                v = W1[((size_t)l*256+k)*1024 + n];
            } else {                                 // W2_t[256][1024]
                int j = r - (WVSA_SZ+WO_SZ+W1_SZ); int n = j >> 10, k = j & 1023;
                v = W2[((size_t)l*1024+k)*256 + n];
            }
            wp[idx] = __float2bfloat16(v);
        } else {
            int i = idx - WTOT; int l = i / 640, n = i - l*640;
            float v = (n < 256) ? bv[l*256+n]
                    : (n < 512) ? bso[l*256+(n-256)]
                                : ba[l*128+(n-512)];
            bp[l*640+n] = v;
        }
    }
}

// ---------------------------------------------------------------- prep (merged src+pos transpose)
__device__ __forceinline__ void tile_decode(int st, int& lvl, int& s0, int& hw, int& start)
{
    if (st < 256)      { lvl=0; s0=st*64;       hw=16384; start=0; }
    else if (st < 320) { lvl=1; s0=(st-256)*64; hw=4096;  start=16384; }
    else if (st < 336) { lvl=2; s0=(st-320)*64; hw=1024;  start=20480; }
    else               { lvl=3; s0=(st-336)*64; hw=256;   start=21504; }
}

__global__ __launch_bounds__(256) void prep_kernel(
    const float* __restrict__ s0p, const float* __restrict__ s1p,
    const float* __restrict__ s2p, const float* __restrict__ s3p,
    const float* __restrict__ p0, const float* __restrict__ p1,
    const float* __restrict__ p2, const float* __restrict__ p3,
    const float* __restrict__ le, bf16* __restrict__ qpos,
    bf16* __restrict__ qb, bf16* __restrict__ qpb)
{
    __shared__ float tileS[32][65];
    __shared__ float tileP[32][65];
    int lvl, s0, hw, start; tile_decode(blockIdx.x, lvl, s0, hw, start);
    const float* sp = lvl==0?s0p : lvl==1?s1p : lvl==2?s2p : s3p;
    const float* pp = lvl==0?p0 : lvl==1?p1 : lvl==2?p2 : p3;
    const int t = threadIdx.x, b = blockIdx.z, c0 = blockIdx.y*32;
#pragma unroll
    for (int j=0;j<8;++j){
        int cl = j*4 + (t>>6), sl = t&63;
        size_t src = ((size_t)b*256 + c0+cl)*hw + s0 + sl;
        tileS[cl][sl] = sp[src];
        tileP[cl][sl] = pp[src];
    }
    __syncthreads();
#pragma unroll
    for (int j=0;j<8;++j){
        int sl = j*8 + (t>>5), cl = t&31;
        float v = tileS[cl][sl];
        float p = tileP[cl][sl] + le[lvl*256 + c0 + cl];
        size_t o = ((size_t)b*N_TOK + start + s0 + sl)*256 + c0 + cl;
        ushort pb = f2b(p);
        qpos[o] = __ushort_as_bfloat16(pb);
        qb[o] = __float2bfloat16(v);
        qpb[o] = __float2bfloat16(v + bfu(pb));
    }
}

// ---------------------------------------------------------------- GEMM (bf16 MFMA)
// 128x128 tile, 4 waves 2x2. Double-buffered 2-phase pipeline.
// MODE 0: N=640 split -> value bf16 | offb bf16 | awb bf16 (A2 for n>=256).
// MODE 1: bf16 out [M][256]. MODE 2: relu bf16 out [M][1024].
template<int MODE>
__global__ __launch_bounds__(256) void gemm_kernel(
    const bf16* __restrict__ A, const bf16* __restrict__ A2,
    const bf16* __restrict__ Wt, const float* __restrict__ bias,
    int K, void* __restrict__ out0, void* __restrict__ out1, void* __restrict__ out2)
{
    __shared__ __align__(1024) ushort As[2][128*32];
    __shared__ __align__(1024) ushort Bs[2][128*32];
    const int tid = threadIdx.x;
    const int lane = tid & 63, w = tid >> 6;
    const int wr = w >> 1, wc = w & 1;
    const int lr = lane & 15, lg = lane >> 4;
    const size_t m0 = (size_t)blockIdx.x * 128;
    const int n0 = blockIdx.y * 128;
    const bf16* Ause = (MODE == 0 && n0 >= 256) ? A2 : A;

    const int srow0 = (w<<5) + (lane>>2);
    const int sphys = (lane&3);
    const int KSTEPS = K >> 5;

    auto stage = [&](int ks, int buf){
        const int k0 = ks*32;
#pragma unroll
        for (int j=0;j<2;++j){
            int row  = srow0 + j*16;
            int slot = sphys ^ ((row>>1)&3);  // pre-swizzled global source
            gload_lds16(&Ause[(m0+row)*(size_t)K + k0 + slot*8], &As[buf][row*32 + sphys*8]);
            gload_lds16(&Wt[(size_t)(n0+row)*K + k0 + slot*8],   &Bs[buf][row*32 + sphys*8]);
        }
    };

    f32x4 acc[4][4];
#pragma unroll
    for (int i=0;i<4;++i)
#pragma unroll
        for (int j=0;j<4;++j) acc[i][j] = (f32x4){0.f,0.f,0.f,0.f};

    stage(0, 0);
    for (int ks = 0; ks < KSTEPS; ++ks) {
        const int cur = ks & 1;
        if (ks + 1 < KSTEPS) {
            stage(ks + 1, cur ^ 1);
            asm volatile("s_waitcnt vmcnt(4)" ::: "memory");
        } else {
            asm volatile("s_waitcnt vmcnt(0)" ::: "memory");
        }
        __builtin_amdgcn_s_barrier();
        bf16x8 av[4], bw[4];
#pragma unroll
        for (int i=0;i<4;++i){
            int ar = wr*64 + i*16 + lr;
            int br = wc*64 + i*16 + lr;
            av[i] = *(bf16x8*)&As[cur][ar*32 + ((lg ^ ((ar>>1)&3))<<3)];
            bw[i] = *(bf16x8*)&Bs[cur][br*32 + ((lg ^ ((br>>1)&3))<<3)];
        }
#pragma unroll
        for (int mi=0;mi<4;++mi)
#pragma unroll
            for (int ni=0;ni<4;++ni)
                acc[mi][ni] = __builtin_amdgcn_mfma_f32_16x16x32_bf16(av[mi], bw[ni], acc[mi][ni], 0,0,0);
        asm volatile("s_waitcnt lgkmcnt(0)" ::: "memory");
        __builtin_amdgcn_sched_barrier(0);
        __builtin_amdgcn_s_barrier();
    }
#pragma unroll
    for (int mi=0;mi<4;++mi){
#pragma unroll
        for (int ni=0;ni<4;++ni){
            int gr0 = (int)m0 + wr*64 + mi*16 + lg*4;
            int gc  = n0 + wc*64 + ni*16 + lr;
            float bb = bias[gc];
#pragma unroll
            for (int r=0;r<4;++r){
                float y = acc[mi][ni][r] + bb;
                size_t row = (size_t)(gr0 + r);
                if (MODE == 0) {
                    if (gc < 256)      ((bf16*)out0)[row*256 + gc] = __float2bfloat16(y);
                    else if (gc < 512) ((bf16*)out1)[row*256 + (gc-256)] = __float2bfloat16(y);
                    else               ((bf16*)out2)[row*128 + (gc-512)] = __float2bfloat16(y);
                } else if (MODE == 1) {
                    ((bf16*)out0)[row*256 + gc] = __float2bfloat16(y);
                } else {
                    ((bf16*)out0)[row*1024 + gc] = __float2bfloat16(fmaxf(y, 0.f));
                }
            }
        }
    }
}

// ---------------------------------------------------------------- deformable sampling
// One wave per 2 tokens: lane = t*32 + h*4 + c; uint4 (16B) gathers; packed
// 20 B/slot LDS table; XCD-swizzled; bf16 offb/awb inputs.
__global__ __launch_bounds__(256) void sample_kernel(
    const bf16* __restrict__ value, const bf16* __restrict__ offb,
    const bf16* __restrict__ awb, bf16* __restrict__ sampled)
{
    __shared__ float tabw[8][136][4];
    __shared__ int   tabo[8][136];
    const int nb = gridDim.x;                 // 5440, % 8 == 0
    const int chunk = nb >> 3;
    const int bid = (blockIdx.x & 7) * chunk + (blockIdx.x >> 3);
    const int wv = threadIdx.x >> 6, lane = threadIdx.x & 63;
    const int t = lane >> 5, L = lane & 31;
    const int tt = wv*2 + t;                  // token slot in block (0..7)
    const int m = bid*8 + tt;

    const int b = m / N_TOK;                  // uniform per block (21760 % 8 == 0)
    const int n = m - b*N_TOK;
    float refx, refy;
    if (n < 16384)      { int s=n;       int qy=s>>7, qx=s&127; refx=(qx+0.5f)*(1.f/128.f); refy=(qy+0.5f)*(1.f/128.f); }
    else if (n < 20480) { int s=n-16384; int qy=s>>6, qx=s&63;  refx=(qx+0.5f)*(1.f/64.f);  refy=(qy+0.5f)*(1.f/64.f); }
    else if (n < 21504) { int s=n-20480; int qy=s>>5, qx=s&31;  refx=(qx+0.5f)*(1.f/32.f);  refy=(qy+0.5f)*(1.f/32.f); }
    else                { int s=n-21504; int qy=s>>4, qx=s&15;  refx=(qx+0.5f)*(1.f/16.f);  refy=(qy+0.5f)*(1.f/16.f); }

    // softmax: 4 logits/lane (bf16); head group = 4 lanes (xor 1,2 stays in group)
    ushort4 av4 = *(const ushort4*)&awb[(size_t)m*128 + L*4];
    float lgx = bfu(av4.x), lgy = bfu(av4.y), lgz = bfu(av4.z), lgw = bfu(av4.w);
    float mx = fmaxf(fmaxf(lgx,lgy), fmaxf(lgz,lgw));
    mx = fmaxf(mx, __shfl_xor(mx,1));
    mx = fmaxf(mx, __shfl_xor(mx,2));
    float e0=__expf(lgx-mx), e1=__expf(lgy-mx), e2=__expf(lgz-mx), e3=__expf(lgw-mx);
    float sm = e0+e1+e2+e3;
    sm += __shfl_xor(sm,1);
    sm += __shfl_xor(sm,2);
    float rs = __frcp_rn(sm);
    float wgt[4] = {e0*rs, e1*rs, e2*rs, e3*rs};

    // offsets: 8 bf16/lane = points 4L..4L+3 (x,y interleaved)
    uint4 ov = *(const uint4*)&offb[(size_t)m*256 + L*8];
    float offx[4] = {bf16_lo(ov.x), bf16_lo(ov.y), bf16_lo(ov.z), bf16_lo(ov.w)};
    float offy[4] = {bf16_hi(ov.x), bf16_hi(ov.y), bf16_hi(ov.z), bf16_hi(ov.w)};

    const int LSTART[4] = {0, 16384, 20480, 21504};
#pragma unroll
    for (int j=0;j<4;++j){
        int pg  = L*4 + j;
        int lvl = (pg >> 2) & 3;
        int wl  = 128 >> lvl;
        float fx = refx*(float)wl - 0.5f + offx[j];
        float fy = refy*(float)wl - 0.5f + offy[j];
        float x0f = floorf(fx), y0f = floorf(fy);
        float dx = fx - x0f, dy = fy - y0f;
        int ix = (int)x0f, iy = (int)y0f;
        int cx0 = min(max(ix,0),   wl-1), cx1 = min(max(ix+1,0), wl-1);
        int cy0 = min(max(iy,0),   wl-1), cy1 = min(max(iy+1,0), wl-1);
        bool vx0 = (unsigned)ix     < (unsigned)wl, vx1 = (unsigned)(ix+1) < (unsigned)wl;
        bool vy0 = (unsigned)iy     < (unsigned)wl, vy1 = (unsigned)(iy+1) < (unsigned)wl;
        float a = 1.f-dx, bb = 1.f-dy;
        int slot = (pg >> 4)*17 + (pg & 15);
        float4 wq;
        wq.x = (vx0&&vy0) ? a*bb*wgt[j] : 0.f;
        wq.y = (vx1&&vy0) ? dx*bb*wgt[j] : 0.f;
        wq.z = (vx0&&vy1) ? a*dy*wgt[j] : 0.f;
        wq.w = (vx1&&vy1) ? dx*dy*wgt[j] : 0.f;
        *(float4*)&tabw[tt][slot][0] = wq;
        int lb = LSTART[lvl];
        int o00 = (lb + cy0*wl + cx0) << 9;
        tabo[tt][slot] = o00 | (cx1 > cx0 ? 1 : 0) | (cy1 > cy0 ? 2 : 0);
    }
    __syncthreads();

    const int h = (lane >> 2) & 7, c = lane & 3;
    const int rb = __builtin_amdgcn_readfirstlane(b);
    const char* vb = (const char*)value + (size_t)rb*N_TOK*512;
    const int laneoff = h*64 + c*16;          // byte offset of 8-channel group
    f32x4 accA = (f32x4){0.f,0.f,0.f,0.f};
    f32x4 accB = (f32x4){0.f,0.f,0.f,0.f};
#pragma unroll 4
    for (int k=0;k<16;++k){
        int slot = h*17 + k;
        float4 w  = *(const float4*)&tabw[tt][slot][0];
        int    io = tabo[tt][slot];
        int o00 = (io & ~511) + laneoff;
        int dxo = (io & 1) << 9;
        int dyo = (io & 2) ? (65536 >> (k >> 2)) : 0;
        uint4 q00 = *(const uint4*)(vb + o00);
        uint4 q01 = *(const uint4*)(vb + (o00 + dxo));
        uint4 q10 = *(const uint4*)(vb + (o00 + dyo));
        uint4 q11 = *(const uint4*)(vb + (o00 + dxo + dyo));
        accA[0] += w.x*bf16_lo(q00.x) + w.y*bf16_lo(q01.x) + w.z*bf16_lo(q10.x) + w.w*bf16_lo(q11.x);
        accA[1] += w.x*bf16_hi(q00.x) + w.y*bf16_hi(q01.x) + w.z*bf16_hi(q10.x) + w.w*bf16_hi(q11.x);
        accA[2] += w.x*bf16_lo(q00.y) + w.y*bf16_lo(q01.y) + w.z*bf16_lo(q10.y) + w.w*bf16_lo(q11.y);
        accA[3] += w.x*bf16_hi(q00.y) + w.y*bf16_hi(q01.y) + w.z*bf16_hi(q10.y) + w.w*bf16_hi(q11.y);
        accB[0] += w.x*bf16_lo(q00.z) + w.y*bf16_lo(q01.z) + w.z*bf16_lo(q10.z) + w.w*bf16_lo(q11.z);
        accB[1] += w.x*bf16_hi(q00.z) + w.y*bf16_hi(q01.z) + w.z*bf16_hi(q10.z) + w.w*bf16_hi(q11.z);
        accB[2] += w.x*bf16_lo(q00.w) + w.y*bf16_lo(q01.w) + w.z*bf16_lo(q10.w) + w.w*bf16_lo(q11.w);
        accB[3] += w.x*bf16_hi(q00.w) + w.y*bf16_hi(q01.w) + w.z*bf16_hi(q10.w) + w.w*bf16_hi(q11.w);
    }
    uint4 outv;
    outv.x = (uint)f2b(accA[0]) | ((uint)f2b(accA[1])<<16);
    outv.y = (uint)f2b(accA[2]) | ((uint)f2b(accA[3])<<16);
    outv.z = (uint)f2b(accB[0]) | ((uint)f2b(accB[1])<<16);
    outv.w = (uint)f2b(accB[2]) | ((uint)f2b(accB[3])<<16);
    *(uint4*)((char*)sampled + (size_t)m*512 + laneoff) = outv;
}

// ---------------------------------------------------------------- residual + LN
template<bool WRITE_QPB>
__global__ __launch_bounds__(256) void ln_kernel(
    bf16* __restrict__ qb, const bf16* __restrict__ delta,
    const float* __restrict__ g, const float* __restrict__ be,
    const bf16* __restrict__ qpos, bf16* __restrict__ qpb, float* __restrict__ dout)
{
    const int wv = threadIdx.x >> 6, lane = threadIdx.x & 63;
    const size_t o = ((size_t)blockIdx.x*4 + wv)*256 + lane*4;
    ushort4 qv = *(const ushort4*)&qb[o];
    ushort4 dv = *(const ushort4*)&delta[o];
    float x0 = bfu(qv.x) + bfu(dv.x);
    float x1 = bfu(qv.y) + bfu(dv.y);
    float x2 = bfu(qv.z) + bfu(dv.z);
    float x3 = bfu(qv.w) + bfu(dv.w);
    float s1 = x0+x1+x2+x3;
    float s2 = x0*x0+x1*x1+x2*x2+x3*x3;
#pragma unroll
    for (int i=1;i<64;i<<=1){ s1 += __shfl_xor(s1,i); s2 += __shfl_xor(s2,i); }
    float mu  = s1 * (1.f/256.f);
    float var = s2 * (1.f/256.f) - mu*mu;
    float rs  = rsqrtf(var + 1e-5f);
    float4 gv = *(const float4*)&g[lane*4];
    float4 bv = *(const float4*)&be[lane*4];
    float y0 = (x0-mu)*rs*gv.x + bv.x;
    float y1 = (x1-mu)*rs*gv.y + bv.y;
    float y2 = (x2-mu)*rs*gv.z + bv.z;
    float y3 = (x3-mu)*rs*gv.w + bv.w;
    ushort4 qo; qo.x=f2b(y0); qo.y=f2b(y1); qo.z=f2b(y2); qo.w=f2b(y3);
    *(ushort4*)&qb[o] = qo;
    if constexpr (WRITE_QPB) {
        ushort4 pv = *(const ushort4*)&qpos[o];
        ushort4 po;
        po.x = f2b(y0 + bfu(pv.x));
        po.y = f2b(y1 + bfu(pv.y));
        po.z = f2b(y2 + bfu(pv.z));
        po.w = f2b(y3 + bfu(pv.w));
        *(ushort4*)&qpb[o] = po;
    }
    if (dout) { *(float4*)&dout[o] = make_float4(y0,y1,y2,y3); }
}

// ---------------------------------------------------------------- launch
extern "C" void kernel_launch(void* const* d_in, const int* in_sizes, int n_in,
                              void* d_out, int out_size, void* d_ws, size_t ws_size,
                              hipStream_t stream)
{
    // setup_inputs() dict order is INTERLEAVED: src0,pos0,src1,pos1,...
    const float* src0 = (const float*)d_in[0];
    const float* pos0 = (const float*)d_in[1];
    const float* src1 = (const float*)d_in[2];
    const float* pos1 = (const float*)d_in[3];
    const float* src2 = (const float*)d_in[4];
    const float* pos2 = (const float*)d_in[5];
    const float* src3 = (const float*)d_in[6];
    const float* pos3 = (const float*)d_in[7];
    const float* le   = (const float*)d_in[8];
    const float* Wv   = (const float*)d_in[9];
    const float* bv   = (const float*)d_in[10];
    const float* Ws   = (const float*)d_in[11];
    const float* bso  = (const float*)d_in[12];
    const float* Wa   = (const float*)d_in[13];
    const float* ba   = (const float*)d_in[14];
    const float* Wo   = (const float*)d_in[15];
    const float* bo   = (const float*)d_in[16];
    const float* g1   = (const float*)d_in[17];
    const float* be1  = (const float*)d_in[18];
    const float* W1   = (const float*)d_in[19];
    const float* b1   = (const float*)d_in[20];
    const float* W2   = (const float*)d_in[21];
    const float* b2   = (const float*)d_in[22];
    const float* g2   = (const float*)d_in[23];
    const float* be2  = (const float*)d_in[24];

    if (ws_size < WS_NEED) {   // diagnostic: absmax ~1e6 means ws too small
        sentinel_kernel<<<1, 1, 0, stream>>>((float*)d_out);
        return;
    }
    char* ws = (char*)d_ws;
    bf16*  qpos   = (bf16*) (ws + OFF_QPOS);
    bf16*  qb     = (bf16*) (ws + OFF_QB);
    bf16*  qpb    = (bf16*) (ws + OFF_QPB);
    bf16*  sampled= (bf16*) (ws + OFF_QPB);   // alias: qpb dead after gemm0
    bf16*  delta2 = (bf16*) (ws + OFF_QPB);   // FFN out; ln2 reads then writes qpb in place
    bf16*  wp     = (bf16*) (ws + OFF_WP);
    float* bp     = (float*)(ws + OFF_BP);
    bf16*  offb   = (bf16*) (ws + OFF_R1);    // gemm0 -> sample (bf16 now)
    bf16*  hidden = (bf16*) (ws + OFF_R1);    // FFN: spans R1+VAL+AW (89.13 MB, exact)
    bf16*  value  = (bf16*) (ws + OFF_VAL);   // gemm0 -> sample
    bf16*  delta1 = (bf16*) (ws + OFF_VAL);   // gemm1 -> ln1 (value dead by then)
    bf16*  awb    = (bf16*) (ws + OFF_AW);    // gemm0 -> sample (bf16 now)

    pack_kernel<<<dim3(4096), 256, 0, stream>>>(Wv, Ws, Wa, Wo, W1, W2, bv, bso, ba, wp, bp);
    prep_kernel<<<dim3(340,8,2), 256, 0, stream>>>(src0,src1,src2,src3,
                                                   pos0,pos1,pos2,pos3, le, qpos, qb, qpb);

    for (int l = 0; l < NLAY; ++l) {
        const bf16* wl_ = wp + (size_t)l*PER_L;
        gemm_kernel<0><<<dim3(340,5), 256, 0, stream>>>(qb, qpb, wl_, bp + l*640, 256,
                                                        value, offb, awb);
        sample_kernel<<<dim3(M_TOT/8), 256, 0, stream>>>(value, offb, awb, sampled);
        gemm_kernel<1><<<dim3(340,2), 256, 0, stream>>>(sampled, nullptr, wl_ + WVSA_SZ,
                                                        bo + l*256, 256, delta1, nullptr, nullptr);
        ln_kernel<false><<<dim3(M_TOT/4), 256, 0, stream>>>(qb, delta1, g1 + l*256, be1 + l*256,
                                                            nullptr, nullptr, nullptr);
        gemm_kernel<2><<<dim3(340,8), 256, 0, stream>>>(qb, nullptr, wl_ + WVSA_SZ + WO_SZ,
                                                        b1 + l*1024, 256, hidden, nullptr, nullptr);
        gemm_kernel<1><<<dim3(340,2), 256, 0, stream>>>(hidden, nullptr,
                                                        wl_ + WVSA_SZ + WO_SZ + W1_SZ,
                                                        b2 + l*256, 1024, delta2, nullptr, nullptr);
        ln_kernel<true><<<dim3(M_TOT/4), 256, 0, stream>>>(qb, delta2, g2 + l*256, be2 + l*256,
                                                           qpos, qpb, (l==NLAY-1) ? (float*)d_out : nullptr);
    }
}

// Round 16
// 1374.928 us; speedup vs baseline: 1.2006x; 1.0747x over previous
//
#include <hip/hip_runtime.h>
#include <hip/hip_bf16.h>
#include <stdint.h>

#define D_MODEL 256
#define N_TOK   21760
#define BATCH   2
#define M_TOT   (BATCH*N_TOK)   // 43520 = 340*128
#define NLAY    6

typedef __hip_bfloat16 bf16;
typedef short bf16x8 __attribute__((ext_vector_type(8)));
typedef float f32x4  __attribute__((ext_vector_type(4)));

// packed per-layer weight block (bf16, transposed to [N][K])
#define WVSA_SZ (640*256)
#define WO_SZ   (256*256)
#define W1_SZ   (1024*256)
#define W2_SZ   (256*1024)
#define PER_L   (WVSA_SZ+WO_SZ+W1_SZ+W2_SZ)  // 753664

// ---- workspace layout (aliased by lifetime) ----
#define SZ_QF   ((size_t)M_TOT*256*4)
#define SZ_BF   ((size_t)M_TOT*256*2)
#define SZ_AW   ((size_t)M_TOT*128*4)
#define SZ_WP   ((size_t)PER_L*NLAY*2)
#define SZ_BP   ((size_t)NLAY*640*4)
#define OFF_QPOS  ((size_t)0)
#define OFF_QB    (OFF_QPOS + SZ_BF)
#define OFF_QPB   (OFF_QB   + SZ_BF)    // sampled | delta2
#define OFF_WP    (OFF_QPB  + SZ_BF)
#define OFF_BP    (OFF_WP   + SZ_WP)
#define OFF_R1    (OFF_BP   + SZ_BP)    // offb bf16 | hidden (spans R1+VAL+AW)
#define OFF_VAL   (OFF_R1   + SZ_QF)    // value bf16 | delta1 bf16
#define OFF_AW    (OFF_VAL  + SZ_BF)    // awb bf16
#define WS_NEED   (OFF_AW   + SZ_AW)

// ---------------------------------------------------------------- helpers
typedef const __attribute__((address_space(1))) void gvoid_t;
typedef __attribute__((address_space(3))) void lvoid_t;
__device__ __forceinline__ void gload_lds16(const void* g, void* l){
    __builtin_amdgcn_global_load_lds((gvoid_t*)g, (lvoid_t*)l, 16, 0, 0);
}
__device__ __forceinline__ float bfu(ushort u){ return __uint_as_float(((uint)u)<<16); }
__device__ __forceinline__ ushort f2b(float f){ return __bfloat16_as_ushort(__float2bfloat16(f)); }
__device__ __forceinline__ float bf16_lo(uint u){ return __uint_as_float(u << 16); }
__device__ __forceinline__ float bf16_hi(uint u){ return __uint_as_float(u & 0xffff0000u); }

// ---------------------------------------------------------------- sentinel
__global__ void sentinel_kernel(float* out) { out[0] = 1.0e6f; }

// ---------------------------------------------------------------- pack
__global__ void pack_kernel(const float* __restrict__ Wv, const float* __restrict__ Ws,
                            const float* __restrict__ Wa, const float* __restrict__ Wo,
                            const float* __restrict__ W1, const float* __restrict__ W2,
                            const float* __restrict__ bv, const float* __restrict__ bso,
                            const float* __restrict__ ba,
                            bf16* __restrict__ wp, float* __restrict__ bp)
{
    const int WTOT = PER_L * NLAY;
    for (int idx = blockIdx.x*blockDim.x + threadIdx.x; idx < WTOT + NLAY*640;
         idx += gridDim.x*blockDim.x) {
        if (idx < WTOT) {
            int l = idx / PER_L, r = idx - l*PER_L;
            float v;
            if (r < WVSA_SZ) {                       // Wvsa_t[640][256]
                int n = r >> 8, k = r & 255;
                if (n < 256)      v = Wv[((size_t)l*256+k)*256 + n];
                else if (n < 512) v = Ws[((size_t)l*256+k)*256 + (n-256)];
                else              v = Wa[((size_t)l*256+k)*128 + (n-512)];
            } else if (r < WVSA_SZ+WO_SZ) {          // Wo_t[256][256]
                int j = r - WVSA_SZ; int n = j >> 8, k = j & 255;
                v = Wo[((size_t)l*256+k)*256 + n];
            } else if (r < WVSA_SZ+WO_SZ+W1_SZ) {    // W1_t[1024][256]
                int j = r - (WVSA_SZ+WO_SZ); int n = j >> 8, k = j & 255;
                v = W1[((size_t)l*256+k)*1024 + n];
            } else {                                 // W2_t[256][1024]
                int j = r - (WVSA_SZ+WO_SZ+W1_SZ); int n = j >> 10, k = j & 1023;
                v = W2[((size_t)l*1024+k)*256 + n];
            }
            wp[idx] = __float2bfloat16(v);
        } else {
            int i = idx - WTOT; int l = i / 640, n = i - l*640;
            float v = (n < 256) ? bv[l*256+n]
                    : (n < 512) ? bso[l*256+(n-256)]
                                : ba[l*128+(n-512)];
            bp[l*640+n] = v;
        }
    }
}

// ---------------------------------------------------------------- prep (merged src+pos transpose)
__device__ __forceinline__ void tile_decode(int st, int& lvl, int& s0, int& hw, int& start)
{
    if (st < 256)      { lvl=0; s0=st*64;       hw=16384; start=0; }
    else if (st < 320) { lvl=1; s0=(st-256)*64; hw=4096;  start=16384; }
    else if (st < 336) { lvl=2; s0=(st-320)*64; hw=1024;  start=20480; }
    else               { lvl=3; s0=(st-336)*64; hw=256;   start=21504; }
}

__global__ __launch_bounds__(256) void prep_kernel(
    const float* __restrict__ s0p, const float* __restrict__ s1p,
    const float* __restrict__ s2p, const float* __restrict__ s3p,
    const float* __restrict__ p0, const float* __restrict__ p1,
    const float* __restrict__ p2, const float* __restrict__ p3,
    const float* __restrict__ le, bf16* __restrict__ qpos,
    bf16* __restrict__ qb, bf16* __restrict__ qpb)
{
    __shared__ float tileS[32][65];
    __shared__ float tileP[32][65];
    int lvl, s0, hw, start; tile_decode(blockIdx.x, lvl, s0, hw, start);
    const float* sp = lvl==0?s0p : lvl==1?s1p : lvl==2?s2p : s3p;
    const float* pp = lvl==0?p0 : lvl==1?p1 : lvl==2?p2 : p3;
    const int t = threadIdx.x, b = blockIdx.z, c0 = blockIdx.y*32;
#pragma unroll
    for (int j=0;j<8;++j){
        int cl = j*4 + (t>>6), sl = t&63;
        size_t src = ((size_t)b*256 + c0+cl)*hw + s0 + sl;
        tileS[cl][sl] = sp[src];
        tileP[cl][sl] = pp[src];
    }
    __syncthreads();
#pragma unroll
    for (int j=0;j<8;++j){
        int sl = j*8 + (t>>5), cl = t&31;
        float v = tileS[cl][sl];
        float p = tileP[cl][sl] + le[lvl*256 + c0 + cl];
        size_t o = ((size_t)b*N_TOK + start + s0 + sl)*256 + c0 + cl;
        ushort pb = f2b(p);
        qpos[o] = __ushort_as_bfloat16(pb);
        qb[o] = __float2bfloat16(v);
        qpb[o] = __float2bfloat16(v + bfu(pb));
    }
}

// ---------------------------------------------------------------- GEMM (bf16 MFMA)
// 128x128 tile, 4 waves 2x2. Double-buffered 2-phase pipeline.
// Grid flattened 1-D; bijective m204 XCD swizzle, y-major within each XCD chunk
// (one XCD owns a contiguous x-range of A-tiles across ALL n-tiles -> A slice
// ~2.8MB @K=256 fits the XCD's private 4MB L2; re-reads become L2 hits).
template<int MODE>
__global__ __launch_bounds__(256) void gemm_kernel(
    const bf16* __restrict__ A, const bf16* __restrict__ A2,
    const bf16* __restrict__ Wt, const float* __restrict__ bias,
    int K, int NY, void* __restrict__ out0, void* __restrict__ out1, void* __restrict__ out2)
{
    __shared__ __align__(1024) ushort As[2][128*32];
    __shared__ __align__(1024) ushort Bs[2][128*32];
    const int tid = threadIdx.x;
    const int lane = tid & 63, w = tid >> 6;
    const int wr = w >> 1, wc = w & 1;
    const int lr = lane & 15, lg = lane >> 4;

    // bijective XCD swizzle (m204), then y-major decode
    const int nwg = gridDim.x;
    const int q = nwg >> 3, r = nwg & 7;
    const int xcd = blockIdx.x & 7, idx = blockIdx.x >> 3;
    const int wg = (xcd < r ? xcd*(q+1) : r*(q+1) + (xcd-r)*q) + idx;
    const size_t m0 = (size_t)(wg / NY) * 128;
    const int n0 = (wg % NY) * 128;
    const bf16* Ause = (MODE == 0 && n0 >= 256) ? A2 : A;

    const int srow0 = (w<<5) + (lane>>2);
    const int sphys = (lane&3);
    const int KSTEPS = K >> 5;

    auto stage = [&](int ks, int buf){
        const int k0 = ks*32;
#pragma unroll
        for (int j=0;j<2;++j){
            int row  = srow0 + j*16;
            int slot = sphys ^ ((row>>1)&3);  // pre-swizzled global source
            gload_lds16(&Ause[(m0+row)*(size_t)K + k0 + slot*8], &As[buf][row*32 + sphys*8]);
            gload_lds16(&Wt[(size_t)(n0+row)*K + k0 + slot*8],   &Bs[buf][row*32 + sphys*8]);
        }
    };

    f32x4 acc[4][4];
#pragma unroll
    for (int i=0;i<4;++i)
#pragma unroll
        for (int j=0;j<4;++j) acc[i][j] = (f32x4){0.f,0.f,0.f,0.f};

    stage(0, 0);
    for (int ks = 0; ks < KSTEPS; ++ks) {
        const int cur = ks & 1;
        if (ks + 1 < KSTEPS) {
            stage(ks + 1, cur ^ 1);
            asm volatile("s_waitcnt vmcnt(4)" ::: "memory");
        } else {
            asm volatile("s_waitcnt vmcnt(0)" ::: "memory");
        }
        __builtin_amdgcn_s_barrier();
        bf16x8 av[4], bw[4];
#pragma unroll
        for (int i=0;i<4;++i){
            int ar = wr*64 + i*16 + lr;
            int br = wc*64 + i*16 + lr;
            av[i] = *(bf16x8*)&As[cur][ar*32 + ((lg ^ ((ar>>1)&3))<<3)];
            bw[i] = *(bf16x8*)&Bs[cur][br*32 + ((lg ^ ((br>>1)&3))<<3)];
        }
#pragma unroll
        for (int mi=0;mi<4;++mi)
#pragma unroll
            for (int ni=0;ni<4;++ni)
                acc[mi][ni] = __builtin_amdgcn_mfma_f32_16x16x32_bf16(av[mi], bw[ni], acc[mi][ni], 0,0,0);
        asm volatile("s_waitcnt lgkmcnt(0)" ::: "memory");
        __builtin_amdgcn_sched_barrier(0);
        __builtin_amdgcn_s_barrier();
    }
#pragma unroll
    for (int mi=0;mi<4;++mi){
#pragma unroll
        for (int ni=0;ni<4;++ni){
            int gr0 = (int)m0 + wr*64 + mi*16 + lg*4;
            int gc  = n0 + wc*64 + ni*16 + lr;
            float bb = bias[gc];
#pragma unroll
            for (int r2=0;r2<4;++r2){
                float y = acc[mi][ni][r2] + bb;
                size_t row = (size_t)(gr0 + r2);
                if (MODE == 0) {
                    if (gc < 256)      ((bf16*)out0)[row*256 + gc] = __float2bfloat16(y);
                    else if (gc < 512) ((bf16*)out1)[row*256 + (gc-256)] = __float2bfloat16(y);
                    else               ((bf16*)out2)[row*128 + (gc-512)] = __float2bfloat16(y);
                } else if (MODE == 1) {
                    ((bf16*)out0)[row*256 + gc] = __float2bfloat16(y);
                } else {
                    ((bf16*)out0)[row*1024 + gc] = __float2bfloat16(fmaxf(y, 0.f));
                }
            }
        }
    }
}

// ---------------------------------------------------------------- deformable sampling
// One wave per 2 tokens: lane = t*32 + h*4 + c; uint4 (16B) gathers; packed
// 20 B/slot LDS table; XCD-swizzled; bf16 offb/awb inputs.
__global__ __launch_bounds__(256) void sample_kernel(
    const bf16* __restrict__ value, const bf16* __restrict__ offb,
    const bf16* __restrict__ awb, bf16* __restrict__ sampled)
{
    __shared__ float tabw[8][136][4];
    __shared__ int   tabo[8][136];
    const int nb = gridDim.x;                 // 5440, % 8 == 0
    const int chunk = nb >> 3;
    const int bid = (blockIdx.x & 7) * chunk + (blockIdx.x >> 3);
    const int wv = threadIdx.x >> 6, lane = threadIdx.x & 63;
    const int t = lane >> 5, L = lane & 31;
    const int tt = wv*2 + t;                  // token slot in block (0..7)
    const int m = bid*8 + tt;

    const int b = m / N_TOK;                  // uniform per block (21760 % 8 == 0)
    const int n = m - b*N_TOK;
    float refx, refy;
    if (n < 16384)      { int s=n;       int qy=s>>7, qx=s&127; refx=(qx+0.5f)*(1.f/128.f); refy=(qy+0.5f)*(1.f/128.f); }
    else if (n < 20480) { int s=n-16384; int qy=s>>6, qx=s&63;  refx=(qx+0.5f)*(1.f/64.f);  refy=(qy+0.5f)*(1.f/64.f); }
    else if (n < 21504) { int s=n-20480; int qy=s>>5, qx=s&31;  refx=(qx+0.5f)*(1.f/32.f);  refy=(qy+0.5f)*(1.f/32.f); }
    else                { int s=n-21504; int qy=s>>4, qx=s&15;  refx=(qx+0.5f)*(1.f/16.f);  refy=(qy+0.5f)*(1.f/16.f); }

    // softmax: 4 logits/lane (bf16); head group = 4 lanes (xor 1,2 stays in group)
    ushort4 av4 = *(const ushort4*)&awb[(size_t)m*128 + L*4];
    float lgx = bfu(av4.x), lgy = bfu(av4.y), lgz = bfu(av4.z), lgw = bfu(av4.w);
    float mx = fmaxf(fmaxf(lgx,lgy), fmaxf(lgz,lgw));
    mx = fmaxf(mx, __shfl_xor(mx,1));
    mx = fmaxf(mx, __shfl_xor(mx,2));
    float e0=__expf(lgx-mx), e1=__expf(lgy-mx), e2=__expf(lgz-mx), e3=__expf(lgw-mx);
    float sm = e0+e1+e2+e3;
    sm += __shfl_xor(sm,1);
    sm += __shfl_xor(sm,2);
    float rs = __frcp_rn(sm);
    float wgt[4] = {e0*rs, e1*rs, e2*rs, e3*rs};

    // offsets: 8 bf16/lane = points 4L..4L+3 (x,y interleaved)
    uint4 ov = *(const uint4*)&offb[(size_t)m*256 + L*8];
    float offx[4] = {bf16_lo(ov.x), bf16_lo(ov.y), bf16_lo(ov.z), bf16_lo(ov.w)};
    float offy[4] = {bf16_hi(ov.x), bf16_hi(ov.y), bf16_hi(ov.z), bf16_hi(ov.w)};

    const int LSTART[4] = {0, 16384, 20480, 21504};
#pragma unroll
    for (int j=0;j<4;++j){
        int pg  = L*4 + j;
        int lvl = (pg >> 2) & 3;
        int wl  = 128 >> lvl;
        float fx = refx*(float)wl - 0.5f + offx[j];
        float fy = refy*(float)wl - 0.5f + offy[j];
        float x0f = floorf(fx), y0f = floorf(fy);
        float dx = fx - x0f, dy = fy - y0f;
        int ix = (int)x0f, iy = (int)y0f;
        int cx0 = min(max(ix,0),   wl-1), cx1 = min(max(ix+1,0), wl-1);
        int cy0 = min(max(iy,0),   wl-1), cy1 = min(max(iy+1,0), wl-1);
        bool vx0 = (unsigned)ix     < (unsigned)wl, vx1 = (unsigned)(ix+1) < (unsigned)wl;
        bool vy0 = (unsigned)iy     < (unsigned)wl, vy1 = (unsigned)(iy+1) < (unsigned)wl;
        float a = 1.f-dx, bb = 1.f-dy;
        int slot = (pg >> 4)*17 + (pg & 15);
        float4 wq;
        wq.x = (vx0&&vy0) ? a*bb*wgt[j] : 0.f;
        wq.y = (vx1&&vy0) ? dx*bb*wgt[j] : 0.f;
        wq.z = (vx0&&vy1) ? a*dy*wgt[j] : 0.f;
        wq.w = (vx1&&vy1) ? dx*dy*wgt[j] : 0.f;
        *(float4*)&tabw[tt][slot][0] = wq;
        int lb = LSTART[lvl];
        int o00 = (lb + cy0*wl + cx0) << 9;
        tabo[tt][slot] = o00 | (cx1 > cx0 ? 1 : 0) | (cy1 > cy0 ? 2 : 0);
    }
    __syncthreads();

    const int h = (lane >> 2) & 7, c = lane & 3;
    const int rb = __builtin_amdgcn_readfirstlane(b);
    const char* vb = (const char*)value + (size_t)rb*N_TOK*512;
    const int laneoff = h*64 + c*16;          // byte offset of 8-channel group
    f32x4 accA = (f32x4){0.f,0.f,0.f,0.f};
    f32x4 accB = (f32x4){0.f,0.f,0.f,0.f};
#pragma unroll 4
    for (int k=0;k<16;++k){
        int slot = h*17 + k;
        float4 w  = *(const float4*)&tabw[tt][slot][0];
        int    io = tabo[tt][slot];
        int o00 = (io & ~511) + laneoff;
        int dxo = (io & 1) << 9;
        int dyo = (io & 2) ? (65536 >> (k >> 2)) : 0;
        uint4 q00 = *(const uint4*)(vb + o00);
        uint4 q01 = *(const uint4*)(vb + (o00 + dxo));
        uint4 q10 = *(const uint4*)(vb + (o00 + dyo));
        uint4 q11 = *(const uint4*)(vb + (o00 + dxo + dyo));
        accA[0] += w.x*bf16_lo(q00.x) + w.y*bf16_lo(q01.x) + w.z*bf16_lo(q10.x) + w.w*bf16_lo(q11.x);
        accA[1] += w.x*bf16_hi(q00.x) + w.y*bf16_hi(q01.x) + w.z*bf16_hi(q10.x) + w.w*bf16_hi(q11.x);
        accA[2] += w.x*bf16_lo(q00.y) + w.y*bf16_lo(q01.y) + w.z*bf16_lo(q10.y) + w.w*bf16_lo(q11.y);
        accA[3] += w.x*bf16_hi(q00.y) + w.y*bf16_hi(q01.y) + w.z*bf16_hi(q10.y) + w.w*bf16_hi(q11.y);
        accB[0] += w.x*bf16_lo(q00.z) + w.y*bf16_lo(q01.z) + w.z*bf16_lo(q10.z) + w.w*bf16_lo(q11.z);
        accB[1] += w.x*bf16_hi(q00.z) + w.y*bf16_hi(q01.z) + w.z*bf16_hi(q10.z) + w.w*bf16_hi(q11.z);
        accB[2] += w.x*bf16_lo(q00.w) + w.y*bf16_lo(q01.w) + w.z*bf16_lo(q10.w) + w.w*bf16_lo(q11.w);
        accB[3] += w.x*bf16_hi(q00.w) + w.y*bf16_hi(q01.w) + w.z*bf16_hi(q10.w) + w.w*bf16_hi(q11.w);
    }
    uint4 outv;
    outv.x = (uint)f2b(accA[0]) | ((uint)f2b(accA[1])<<16);
    outv.y = (uint)f2b(accA[2]) | ((uint)f2b(accA[3])<<16);
    outv.z = (uint)f2b(accB[0]) | ((uint)f2b(accB[1])<<16);
    outv.w = (uint)f2b(accB[2]) | ((uint)f2b(accB[3])<<16);
    *(uint4*)((char*)sampled + (size_t)m*512 + laneoff) = outv;
}

// ---------------------------------------------------------------- residual + LN
template<bool WRITE_QPB>
__global__ __launch_bounds__(256) void ln_kernel(
    bf16* __restrict__ qb, const bf16* __restrict__ delta,
    const float* __restrict__ g, const float* __restrict__ be,
    const bf16* __restrict__ qpos, bf16* __restrict__ qpb, float* __restrict__ dout)
{
    const int wv = threadIdx.x >> 6, lane = threadIdx.x & 63;
    const size_t o = ((size_t)blockIdx.x*4 + wv)*256 + lane*4;
    ushort4 qv = *(const ushort4*)&qb[o];
    ushort4 dv = *(const ushort4*)&delta[o];
    float x0 = bfu(qv.x) + bfu(dv.x);
    float x1 = bfu(qv.y) + bfu(dv.y);
    float x2 = bfu(qv.z) + bfu(dv.z);
    float x3 = bfu(qv.w) + bfu(dv.w);
    float s1 = x0+x1+x2+x3;
    float s2 = x0*x0+x1*x1+x2*x2+x3*x3;
#pragma unroll
    for (int i=1;i<64;i<<=1){ s1 += __shfl_xor(s1,i); s2 += __shfl_xor(s2,i); }
    float mu  = s1 * (1.f/256.f);
    float var = s2 * (1.f/256.f) - mu*mu;
    float rs  = rsqrtf(var + 1e-5f);
    float4 gv = *(const float4*)&g[lane*4];
    float4 bv = *(const float4*)&be[lane*4];
    float y0 = (x0-mu)*rs*gv.x + bv.x;
    float y1 = (x1-mu)*rs*gv.y + bv.y;
    float y2 = (x2-mu)*rs*gv.z + bv.z;
    float y3 = (x3-mu)*rs*gv.w + bv.w;
    ushort4 qo; qo.x=f2b(y0); qo.y=f2b(y1); qo.z=f2b(y2); qo.w=f2b(y3);
    *(ushort4*)&qb[o] = qo;
    if constexpr (WRITE_QPB) {
        ushort4 pv = *(const ushort4*)&qpos[o];
        ushort4 po;
        po.x = f2b(y0 + bfu(pv.x));
        po.y = f2b(y1 + bfu(pv.y));
        po.z = f2b(y2 + bfu(pv.z));
        po.w = f2b(y3 + bfu(pv.w));
        *(ushort4*)&qpb[o] = po;
    }
    if (dout) { *(float4*)&dout[o] = make_float4(y0,y1,y2,y3); }
}

// ---------------------------------------------------------------- launch
extern "C" void kernel_launch(void* const* d_in, const int* in_sizes, int n_in,
                              void* d_out, int out_size, void* d_ws, size_t ws_size,
                              hipStream_t stream)
{
    // setup_inputs() dict order is INTERLEAVED: src0,pos0,src1,pos1,...
    const float* src0 = (const float*)d_in[0];
    const float* pos0 = (const float*)d_in[1];
    const float* src1 = (const float*)d_in[2];
    const float* pos1 = (const float*)d_in[3];
    const float* src2 = (const float*)d_in[4];
    const float* pos2 = (const float*)d_in[5];
    const float* src3 = (const float*)d_in[6];
    const float* pos3 = (const float*)d_in[7];
    const float* le   = (const float*)d_in[8];
    const float* Wv   = (const float*)d_in[9];
    const float* bv   = (const float*)d_in[10];
    const float* Ws   = (const float*)d_in[11];
    const float* bso  = (const float*)d_in[12];
    const float* Wa   = (const float*)d_in[13];
    const float* ba   = (const float*)d_in[14];
    const float* Wo   = (const float*)d_in[15];
    const float* bo   = (const float*)d_in[16];
    const float* g1   = (const float*)d_in[17];
    const float* be1  = (const float*)d_in[18];
    const float* W1   = (const float*)d_in[19];
    const float* b1   = (const float*)d_in[20];
    const float* W2   = (const float*)d_in[21];
    const float* b2   = (const float*)d_in[22];
    const float* g2   = (const float*)d_in[23];
    const float* be2  = (const float*)d_in[24];

    if (ws_size < WS_NEED) {   // diagnostic: absmax ~1e6 means ws too small
        sentinel_kernel<<<1, 1, 0, stream>>>((float*)d_out);
        return;
    }
    char* ws = (char*)d_ws;
    bf16*  qpos   = (bf16*) (ws + OFF_QPOS);
    bf16*  qb     = (bf16*) (ws + OFF_QB);
    bf16*  qpb    = (bf16*) (ws + OFF_QPB);
    bf16*  sampled= (bf16*) (ws + OFF_QPB);   // alias: qpb dead after gemm0
    bf16*  delta2 = (bf16*) (ws + OFF_QPB);   // FFN out; ln2 reads then writes qpb in place
    bf16*  wp     = (bf16*) (ws + OFF_WP);
    float* bp     = (float*)(ws + OFF_BP);
    bf16*  offb   = (bf16*) (ws + OFF_R1);    // gemm0 -> sample (bf16)
    bf16*  hidden = (bf16*) (ws + OFF_R1);    // FFN: spans R1+VAL+AW (89.13 MB, exact)
    bf16*  value  = (bf16*) (ws + OFF_VAL);   // gemm0 -> sample
    bf16*  delta1 = (bf16*) (ws + OFF_VAL);   // gemm1 -> ln1 (value dead by then)
    bf16*  awb    = (bf16*) (ws + OFF_AW);    // gemm0 -> sample (bf16)

    pack_kernel<<<dim3(4096), 256, 0, stream>>>(Wv, Ws, Wa, Wo, W1, W2, bv, bso, ba, wp, bp);
    prep_kernel<<<dim3(340,8,2), 256, 0, stream>>>(src0,src1,src2,src3,
                                                   pos0,pos1,pos2,pos3, le, qpos, qb, qpb);

    for (int l = 0; l < NLAY; ++l) {
        const bf16* wl_ = wp + (size_t)l*PER_L;
        gemm_kernel<0><<<dim3(340*5), 256, 0, stream>>>(qb, qpb, wl_, bp + l*640, 256, 5,
                                                        value, offb, awb);
        sample_kernel<<<dim3(M_TOT/8), 256, 0, stream>>>(value, offb, awb, sampled);
        gemm_kernel<1><<<dim3(340*2), 256, 0, stream>>>(sampled, nullptr, wl_ + WVSA_SZ,
                                                        bo + l*256, 256, 2, delta1, nullptr, nullptr);
        ln_kernel<false><<<dim3(M_TOT/4), 256, 0, stream>>>(qb, delta1, g1 + l*256, be1 + l*256,
                                                            nullptr, nullptr, nullptr);
        gemm_kernel<2><<<dim3(340*8), 256, 0, stream>>>(qb, nullptr, wl_ + WVSA_SZ + WO_SZ,
                                                        b1 + l*1024, 256, 8, hidden, nullptr, nullptr);
        gemm_kernel<1><<<dim3(340*2), 256, 0, stream>>>(hidden, nullptr,
                                                        wl_ + WVSA_SZ + WO_SZ + W1_SZ,
                                                        b2 + l*256, 1024, 2, delta2, nullptr, nullptr);
        ln_kernel<true><<<dim3(M_TOT/4), 256, 0, stream>>>(qb, delta2, g2 + l*256, be2 + l*256,
                                                           qpos, qpb, (l==NLAY-1) ? (float*)d_out : nullptr);
    }
}